// Round 6
// baseline (1134.193 us; speedup 1.0000x reference)
//
#include <hip/hip_runtime.h>

// ---------------- constants ----------------
#define S_LEN 2048
#define NH 32
#define NKV 8
#define HD 128
#define DMODEL 4096
#define MROWS 4096   // B*S
#define QKVN 6144    // 4096 q + 1024 k + 1024 v output cols

typedef short s16x8 __attribute__((ext_vector_type(8)));
typedef float fx4 __attribute__((ext_vector_type(4)));

__device__ __forceinline__ unsigned short f2bf(float f) {
  unsigned int u = __float_as_uint(f);
  u += 0x7fffu + ((u >> 16) & 1u);   // round-to-nearest-even
  return (unsigned short)(u >> 16);
}
__device__ __forceinline__ float bf2f(unsigned short h) {
  return __uint_as_float(((unsigned int)h) << 16);
}

#define GLDS16(gp, lp)                                                        \
  __builtin_amdgcn_global_load_lds(                                           \
      (const __attribute__((address_space(1))) void*)(gp),                    \
      (__attribute__((address_space(3))) void*)(lp), 16, 0, 0)

#define MFMA16(a, b, c) __builtin_amdgcn_mfma_f32_16x16x32_bf16((a), (b), (c), 0, 0, 0)

// ---------------- fused f32 -> bf16 casts (all 5 tensors, one launch) ----------------
__global__ __launch_bounds__(256) void cast_all_k(const float* __restrict__ hs,
                                                  const float* __restrict__ Wq,
                                                  const float* __restrict__ Wk,
                                                  const float* __restrict__ Wv,
                                                  const float* __restrict__ Wo,
                                                  unsigned short* __restrict__ hsb,
                                                  unsigned short* __restrict__ wqkvb,
                                                  unsigned short* __restrict__ wob) {
  int i = blockIdx.x * 256 + threadIdx.x;
  const float* src;
  unsigned short* dst;
  int off;
  if (i < 4194304)       { src = hs; dst = hsb;                off = 0; }
  else if (i < 8388608)  { src = Wq; dst = wqkvb;              off = 4194304; }
  else if (i < 9437184)  { src = Wk; dst = wqkvb + 16777216;   off = 8388608; }
  else if (i < 10485760) { src = Wv; dst = wqkvb + 20971520;   off = 9437184; }
  else                   { src = Wo; dst = wob;                off = 10485760; }
  int j = i - off;
  float4 v = *(const float4*)(src + (size_t)j * 4);
  ushort4 o;
  o.x = f2bf(v.x); o.y = f2bf(v.y); o.z = f2bf(v.z); o.w = f2bf(v.w);
  *(ushort4*)(dst + (size_t)j * 4) = o;
}

// ---------------- bf16 GEMM: C[M,N] = A[M,K] * Bt[N,K]^T ----------------
// VERIFIED m97-structure (rounds 1-2,5) + bijective XCD block swizzle.
__global__ __launch_bounds__(256) void gemm_bt(const unsigned short* __restrict__ A,
                                               const unsigned short* __restrict__ Bt,
                                               float* __restrict__ Cf,
                                               unsigned short* __restrict__ Cb,
                                               int M, int N, int K, int bf16out) {
  __shared__ unsigned short As[128 * 32];
  __shared__ unsigned short Bs[128 * 32];
  const int tid = threadIdx.x;
  const int lane = tid & 63;
  const int w = tid >> 6;
  const int nwg = gridDim.x;
  const int wgs = (blockIdx.x & 7) * (nwg >> 3) + (blockIdx.x >> 3);  // XCD swizzle
  const int ntn = N >> 7;
  const int tm = wgs / ntn;
  const int tn = wgs % ntn;
  const int wm = (w >> 1) << 6;
  const int wn = (w & 1) << 6;

  const int sr = tid >> 2;
  const int kc = (tid & 3) << 3;
  const unsigned short* Ag = A + (size_t)(tm * 128 + sr) * K + kc;
  const unsigned short* Bg = Bt + (size_t)(tn * 128 + sr) * K + kc;
  unsigned short* lA = As + tid * 8;
  unsigned short* lB = Bs + tid * 8;
  const size_t half = (size_t)64 * K;

  fx4 acc[4][4] = {};

  const int opr = lane & 15;
  const int opk = (lane >> 4) << 3;

  for (int k0 = 0; k0 < K; k0 += 32) {
    GLDS16(Ag + k0, lA);
    GLDS16(Ag + half + k0, lA + 2048);
    GLDS16(Bg + k0, lB);
    GLDS16(Bg + half + k0, lB + 2048);
    __syncthreads();
    s16x8 af[4], bf[4];
#pragma unroll
    for (int i = 0; i < 4; ++i)
      af[i] = *(const s16x8*)(As + (wm + i * 16 + opr) * 32 + opk);
#pragma unroll
    for (int j = 0; j < 4; ++j)
      bf[j] = *(const s16x8*)(Bs + (wn + j * 16 + opr) * 32 + opk);
#pragma unroll
    for (int i = 0; i < 4; ++i)
#pragma unroll
      for (int j = 0; j < 4; ++j)
        acc[i][j] = MFMA16(af[i], bf[j], acc[i][j]);
    __syncthreads();
  }

  const int cm = (lane >> 4) << 2;
  const int cn = lane & 15;
#pragma unroll
  for (int i = 0; i < 4; ++i)
#pragma unroll
    for (int j = 0; j < 4; ++j) {
      int row = tm * 128 + wm + i * 16 + cm;
      int col = tn * 128 + wn + j * 16 + cn;
#pragma unroll
      for (int r = 0; r < 4; ++r) {
        float v = acc[i][j][r];
        if (bf16out) Cb[(size_t)(row + r) * N + col] = f2bf(v);
        else         Cf[(size_t)(row + r) * N + col] = v;
      }
    }
}

// ---------------- bf16 transpose: out[C][R] = in[R][C]^T (in rows strided) ----------------
__global__ __launch_bounds__(256) void transpose_k(const unsigned short* __restrict__ in,
                                                   unsigned short* __restrict__ out,
                                                   int R, int C, int istride) {
  __shared__ unsigned short T[64][68];
  const int tid = threadIdx.x;
  const int nbc = C >> 6;
  const int br = blockIdx.x / nbc;
  const int bc = blockIdx.x % nbc;
  const int r0 = br << 6, c0 = bc << 6;
#pragma unroll
  for (int i = 0; i < 4; ++i) {
    int row = i * 16 + (tid >> 4);
    int col = (tid & 15) << 2;
    *(ushort4*)&T[row][col] = *(const ushort4*)(in + (size_t)(r0 + row) * istride + c0 + col);
  }
  __syncthreads();
#pragma unroll
  for (int i = 0; i < 4; ++i) {
    int row = i * 16 + (tid >> 4);
    int col = (tid & 15) << 2;
    ushort4 v;
    v.x = T[col + 0][row]; v.y = T[col + 1][row];
    v.z = T[col + 2][row]; v.w = T[col + 3][row];
    *(ushort4*)(out + (size_t)(c0 + row) * R + r0 + col) = v;
  }
}

// ---------------- RoPE cos/sin table: tab[s*64+d] = (cos, sin) ----------------
__global__ __launch_bounds__(256) void rope_tab_k(const float* __restrict__ freqs,
                                                  const int* __restrict__ pos,
                                                  float2* __restrict__ tab) {
  int i = blockIdx.x * 256 + threadIdx.x;  // S*64 = 131072
  int s = i >> 6, d = i & 63;
  float ang = freqs[((size_t)(pos[0] + s) << 6) + d];
  float sv, cv;
  sincosf(ang, &sv, &cv);
  tab[i] = make_float2(cv, sv);
}

// ---------------- RoPE apply, in-place on merged qkv buffer (row stride QKVN) ----------------
__global__ __launch_bounds__(256) void rope_k(unsigned short* __restrict__ qkv,
                                              const float2* __restrict__ tab) {
  int idx = blockIdx.x * 256 + threadIdx.x;  // 4096 * 40 * 64
  int d2 = idx & 63;
  int t = idx >> 6;
  int hh = t % (NH + NKV);
  int row = t / (NH + NKV);
  int s = row & (S_LEN - 1);
  float2 cs = tab[(s << 6) + d2];
  unsigned short* p = qkv + (size_t)row * QKVN +
                      (hh < NH ? hh * HD : DMODEL + (hh - NH) * HD) + (d2 << 1);
  unsigned int xy = *(unsigned int*)p;
  float x1 = bf2f((unsigned short)(xy & 0xffffu));
  float x2 = bf2f((unsigned short)(xy >> 16));
  float o1 = x1 * cs.x - x2 * cs.y;
  float o2 = x1 * cs.y + x2 * cs.x;
  *(unsigned int*)p = (unsigned int)f2bf(o1) | ((unsigned int)f2bf(o2) << 16);
}

// ---------------- MFMA flash attention, swapped-operand / global-frag design ----------------
// 4 independent waves per block (NO barriers, NO K/V LDS staging). Wave owns 32
// q-rows. S^T = MFMA(K-rows, Q-rows): softmax columns are lane-local (q = cn),
// reduces are 2 shfl_xor per qb. P routed via wave-private LDS [32][72].
// O^T = MFMA(V^T-rows, P-rows). K/V frags read direct from global (L2-resident;
// chunked XCD mapping keeps <=2 (b,kv) working sets per XCD L2).
__global__ __launch_bounds__(256) void attn_mfma(const unsigned short* __restrict__ qkv,
                                                 const unsigned short* __restrict__ vtb,
                                                 unsigned short* __restrict__ aob) {
  __shared__ alignas(16) unsigned short Ps[4][32 * 72];  // 18 KB total
  const int tid = threadIdx.x;
  const int lane = tid & 63;
  const int w = tid >> 6;
  // chunked XCD swizzle: XCD x gets logical blocks [x*128, x*128+128) = 2 (b,kv) groups
  const int lg = (blockIdx.x & 7) * 128 + (blockIdx.x >> 3);  // grid = 1024
  const int qc = lg & 15;            // 16 q-chunks of 128 rows
  const int hsub = (lg >> 4) & 3;    // head within kv group
  const int kvi = (lg >> 6) & 7;
  const int b = lg >> 9;
  const int h = kvi * 4 + hsub;

  const int opr = lane & 15;         // operand row within 16
  const int g = lane >> 4;           // k-subblock 0..3
  const int ak = g * 8;              // operand k offset (shorts)
  const int cm = g * 4;              // C/D row base
  const int cn = opr;                // C/D col

  const int qrow0 = b * S_LEN + qc * 128 + w * 32;
  const unsigned short* kptr = qkv + (size_t)(b * S_LEN) * QKVN + DMODEL + kvi * HD;
  const unsigned short* vptr = vtb + (size_t)(kvi * HD) * MROWS + b * S_LEN;
  unsigned short* Pw = Ps[w];

  // ---- Q b-frags hoisted (8 x 16B direct global) ----
  s16x8 qf[2][4];
#pragma unroll
  for (int qb = 0; qb < 2; ++qb)
#pragma unroll
    for (int kk = 0; kk < 4; ++kk)
      qf[qb][kk] = *(const s16x8*)(qkv + (size_t)(qrow0 + qb * 16 + opr) * QKVN +
                                   h * HD + kk * 32 + ak);

  float m_run[2] = {-1e30f, -1e30f};
  float l_run[2] = {0.f, 0.f};
  fx4 acc[8][2] = {};
  const float scale = 0.08838834764831845f;  // 1/sqrt(128)

  for (int t0 = 0; t0 < S_LEN; t0 += 64) {
    // ---- S^T[key][q] = MFMA(K, Q) over d=128 ----
    fx4 st[4][2] = {};
#pragma unroll
    for (int kb2 = 0; kb2 < 4; ++kb2) {
      s16x8 kf[4];
#pragma unroll
      for (int kk = 0; kk < 4; ++kk)
        kf[kk] = *(const s16x8*)(kptr + (size_t)(t0 + kb2 * 16 + opr) * QKVN + kk * 32 + ak);
#pragma unroll
      for (int qb = 0; qb < 2; ++qb)
#pragma unroll
        for (int kk = 0; kk < 4; ++kk)
          st[kb2][qb] = MFMA16(kf[kk], qf[qb][kk], st[kb2][qb]);
    }

    // ---- softmax per q-column (q = qb*16 + cn); keys spread over kb2, r, g ----
    float mloc[2], alpha[2], psum[2];
#pragma unroll
    for (int qb = 0; qb < 2; ++qb) {
      float mm = -1e30f;
#pragma unroll
      for (int kb2 = 0; kb2 < 4; ++kb2)
#pragma unroll
        for (int r = 0; r < 4; ++r) mm = fmaxf(mm, st[kb2][qb][r] * scale);
      mm = fmaxf(mm, __shfl_xor(mm, 16));
      mm = fmaxf(mm, __shfl_xor(mm, 32));
      mloc[qb] = mm;
      float mnew = fmaxf(m_run[qb], mm);
      alpha[qb] = __expf(m_run[qb] - mnew);   // first tile: exp(-huge) = 0
      m_run[qb] = mnew;
      psum[qb] = 0.f;
    }
    // rescale running output and l
#pragma unroll
    for (int db = 0; db < 8; ++db)
#pragma unroll
      for (int qb = 0; qb < 2; ++qb)
#pragma unroll
        for (int r = 0; r < 4; ++r) acc[db][qb][r] *= alpha[qb];

    // ---- p = exp(s - m); accumulate psum; store bf16 P[q][key] to LDS ----
#pragma unroll
    for (int kb2 = 0; kb2 < 4; ++kb2)
#pragma unroll
      for (int qb = 0; qb < 2; ++qb)
#pragma unroll
        for (int r = 0; r < 4; ++r) {
          float pv = __expf(st[kb2][qb][r] * scale - m_run[qb]);
          psum[qb] += pv;
          Pw[(qb * 16 + cn) * 72 + kb2 * 16 + cm + r] = f2bf(pv);
        }
#pragma unroll
    for (int qb = 0; qb < 2; ++qb) {
      float s = psum[qb];
      s += __shfl_xor(s, 16);
      s += __shfl_xor(s, 32);
      l_run[qb] = l_run[qb] * alpha[qb] + s;
    }

    // ---- P b-frags (wave-private LDS; same-wave DS ops are in-order) ----
    s16x8 pf[2][2];
#pragma unroll
    for (int qb = 0; qb < 2; ++qb)
#pragma unroll
      for (int tb = 0; tb < 2; ++tb)
        pf[qb][tb] = *(const s16x8*)(Pw + (qb * 16 + opr) * 72 + tb * 32 + ak);

    // ---- O^T += MFMA(V^T, P) over t=64 ----
#pragma unroll
    for (int db = 0; db < 8; ++db) {
      s16x8 vf[2];
#pragma unroll
      for (int tb = 0; tb < 2; ++tb)
        vf[tb] = *(const s16x8*)(vptr + (size_t)(db * 16 + opr) * MROWS + t0 + tb * 32 + ak);
#pragma unroll
      for (int qb = 0; qb < 2; ++qb)
#pragma unroll
        for (int tb = 0; tb < 2; ++tb)
          acc[db][qb] = MFMA16(vf[tb], pf[qb][tb], acc[db][qb]);
    }
  }

  // ---- epilogue: normalize per q (lane-local), pack 4 consecutive d -> 8B store ----
  float inv[2] = {1.0f / l_run[0], 1.0f / l_run[1]};
#pragma unroll
  for (int db = 0; db < 8; ++db)
#pragma unroll
    for (int qb = 0; qb < 2; ++qb) {
      ushort4 o;
      o.x = f2bf(acc[db][qb][0] * inv[qb]);
      o.y = f2bf(acc[db][qb][1] * inv[qb]);
      o.z = f2bf(acc[db][qb][2] * inv[qb]);
      o.w = f2bf(acc[db][qb][3] * inv[qb]);
      *(ushort4*)(aob + (size_t)(qrow0 + qb * 16 + cn) * DMODEL + h * HD + db * 16 + cm) = o;
    }
}

// ---------------- launch ----------------
extern "C" void kernel_launch(void* const* d_in, const int* in_sizes, int n_in,
                              void* d_out, int out_size, void* d_ws, size_t ws_size,
                              hipStream_t stream) {
  const float* hs = (const float*)d_in[0];
  const float* fr = (const float*)d_in[1];
  const float* Wq = (const float*)d_in[2];
  const float* Wk = (const float*)d_in[3];
  const float* Wv = (const float*)d_in[4];
  const float* Wo = (const float*)d_in[5];
  const int* pos = (const int*)d_in[6];
  float* out = (float*)d_out;

  // workspace (bf16 elems), total 83,886,080 shorts = 167.8 MB
  unsigned short* w = (unsigned short*)d_ws;
  unsigned short* hsb   = w; w += 16777216;  // [4096,4096] hs bf16 (tab reuses after QKV gemm)
  unsigned short* wqkvb = w; w += 25165824;  // [6144,4096] Wq|Wk|Wv  (aob+vtb reuse after gemm)
  unsigned short* wob   = w; w += 16777216;  // [4096,4096]
  unsigned short* qkvb  = w; w += 25165824;  // [4096,6144] q|k|v per row (rope in-place)
  unsigned short* aob = wqkvb;               // [4096,4096] attn out
  unsigned short* vtb = wqkvb + 16777216;    // [1024,4096] V^T
  float2* tab = (float2*)hsb;                // [2048*64] cos/sin

  if (ws_size < (size_t)83886080 * 2) return;

  cast_all_k<<<57344, 256, 0, stream>>>(hs, Wq, Wk, Wv, Wo, hsb, wqkvb, wob);

  // fused QKV projection: [4096,4096] x [6144,4096]^T -> [4096,6144]
  gemm_bt<<<1536, 256, 0, stream>>>(hsb, wqkvb, nullptr, qkvb, MROWS, QKVN, DMODEL, 1);

  rope_tab_k<<<512, 256, 0, stream>>>(fr, pos, tab);   // hsb dead now
  rope_k<<<40960, 256, 0, stream>>>(qkvb, tab);

  transpose_k<<<1024, 256, 0, stream>>>(qkvb + 5120, vtb, MROWS, 1024, QKVN);  // V -> V^T

  attn_mfma<<<1024, 256, 0, stream>>>(qkvb, vtb, aob);

  // output projection: [4096,4096] x [4096,4096]^T -> f32 out
  gemm_bt<<<1024, 256, 0, stream>>>(aob, wob, out, nullptr, MROWS, DMODEL, DMODEL, 0);
}

// Round 7
// 749.964 us; speedup vs baseline: 1.5123x; 1.5123x over previous
//
#include <hip/hip_runtime.h>

// ---------------- constants ----------------
#define S_LEN 2048
#define NH 32
#define NKV 8
#define HD 128
#define DMODEL 4096
#define MROWS 4096   // B*S
#define QKVN 6144    // 4096 q + 1024 k + 1024 v output cols

typedef short s16x8 __attribute__((ext_vector_type(8)));
typedef float fx4 __attribute__((ext_vector_type(4)));

__device__ __forceinline__ unsigned short f2bf(float f) {
  unsigned int u = __float_as_uint(f);
  u += 0x7fffu + ((u >> 16) & 1u);   // round-to-nearest-even
  return (unsigned short)(u >> 16);
}
__device__ __forceinline__ float bf2f(unsigned short h) {
  return __uint_as_float(((unsigned int)h) << 16);
}

#define GLDS16(gp, lp)                                                        \
  __builtin_amdgcn_global_load_lds(                                           \
      (const __attribute__((address_space(1))) void*)(gp),                    \
      (__attribute__((address_space(3))) void*)(lp), 16, 0, 0)

#define MFMA16(a, b, c) __builtin_amdgcn_mfma_f32_16x16x32_bf16((a), (b), (c), 0, 0, 0)

// ---------------- fused f32 -> bf16 casts (all 5 tensors, one launch) ----------------
__global__ __launch_bounds__(256) void cast_all_k(const float* __restrict__ hs,
                                                  const float* __restrict__ Wq,
                                                  const float* __restrict__ Wk,
                                                  const float* __restrict__ Wv,
                                                  const float* __restrict__ Wo,
                                                  unsigned short* __restrict__ hsb,
                                                  unsigned short* __restrict__ wqkvb,
                                                  unsigned short* __restrict__ wob) {
  int i = blockIdx.x * 256 + threadIdx.x;
  const float* src;
  unsigned short* dst;
  int off;
  if (i < 4194304)       { src = hs; dst = hsb;                off = 0; }
  else if (i < 8388608)  { src = Wq; dst = wqkvb;              off = 4194304; }
  else if (i < 9437184)  { src = Wk; dst = wqkvb + 16777216;   off = 8388608; }
  else if (i < 10485760) { src = Wv; dst = wqkvb + 20971520;   off = 9437184; }
  else                   { src = Wo; dst = wob;                off = 10485760; }
  int j = i - off;
  float4 v = *(const float4*)(src + (size_t)j * 4);
  ushort4 o;
  o.x = f2bf(v.x); o.y = f2bf(v.y); o.z = f2bf(v.z); o.w = f2bf(v.w);
  *(ushort4*)(dst + (size_t)j * 4) = o;
}

// ---------------- 256x256 8-phase bf16 GEMM: C[M,N] = A[M,K] * Bt[N,K]^T ----------------
// 512 thr = 8 waves (2M x 4N), BK=64, double-buffered 128 KiB LDS, XOR-swizzled
// 128B rows (byte ^= (row&7)<<4), counted vmcnt(8) (never 0 in loop).
// Race-freedom proof (audited R7):
//  - stage(t+2) into buf[cur] is issued only AFTER the phase-end barrier that
//    every wave reaches only after lgkmcnt(0) completed its reads of that
//    region (A fully read after phase 1; B after phase 2).
//  - reads of tile t+1 begin only after vmcnt(8)+barrier drained t+1's 8
//    per-wave stage loads (prologue: 16 issued, vmcnt(8) -> tile 0 landed).
//  - swizzle applied identically (involution) on pre-swizzled global source
//    and ds_read; LDS destination stays linear (wave-uniform base + lane*16).
__global__ __launch_bounds__(512, 2) void gemm256(const unsigned short* __restrict__ A,
                                                  const unsigned short* __restrict__ Bt,
                                                  float* __restrict__ Cf,
                                                  unsigned short* __restrict__ Cb,
                                                  int M, int N, int K, int bf16out) {
  __shared__ unsigned short Abuf[2][16384];  // [2][256 rows][64 cols]
  __shared__ unsigned short Bbuf[2][16384];
  const int tid = threadIdx.x;
  const int lane = tid & 63;
  const int w = tid >> 6;
  const int wm = w >> 2;   // 0..1
  const int wn = w & 3;    // 0..3

  const int nwg = gridDim.x;
  const int wg = (blockIdx.x & 7) * (nwg >> 3) + (blockIdx.x >> 3);  // XCD swizzle
  const int ntn = N >> 8;
  const int tm = wg / ntn;
  const int tn = wg % ntn;

  const int opr = lane & 15;
  const int opk2 = (lane >> 4) << 4;   // byte offset {0,16,32,48}
  const int NT = K >> 6;

  const unsigned short* Agbase = A + (size_t)(tm * 256) * K;
  const unsigned short* Bgbase = Bt + (size_t)(tn * 256) * K;
  const int abase = wm * 16384 + wn * 4096;  // bytes; rows [wm*128+wn*32, +32)
  const int bbase = (wn >> 1) * 16384 + (wm * 2 + (wn & 1)) * 4096;

  auto stageA = [&](int bsel, int kt) {
#pragma unroll
    for (int r = 0; r < 4; ++r) {
      const int d = abase + r * 1024 + lane * 16;
      const int row = d >> 7;
      const int u = (d & 127) ^ ((row & 7) << 4);
      GLDS16(Agbase + (size_t)row * K + kt * 64 + (u >> 1), (char*)&Abuf[bsel][0] + d);
    }
  };
  auto stageB = [&](int bsel, int kt) {
#pragma unroll
    for (int r = 0; r < 4; ++r) {
      const int d = bbase + r * 1024 + lane * 16;
      const int row = d >> 7;
      const int u = (d & 127) ^ ((row & 7) << 4);
      GLDS16(Bgbase + (size_t)row * K + kt * 64 + (u >> 1), (char*)&Bbuf[bsel][0] + d);
    }
  };

  fx4 acc[8][4] = {};

  stageA(0, 0); stageB(0, 0);
  stageA(1, 1); stageB(1, 1);
  asm volatile("s_waitcnt vmcnt(8)" ::: "memory");
  __builtin_amdgcn_s_barrier();

#define PH_SYNC()                                            \
  do {                                                       \
    __builtin_amdgcn_s_barrier();                            \
    asm volatile("s_waitcnt lgkmcnt(0)" ::: "memory");       \
    __builtin_amdgcn_sched_barrier(0);                       \
  } while (0)

#pragma unroll 1
  for (int t = 0; t < NT; ++t) {
    const int cur = t & 1;
    const unsigned short* Abc = Abuf[cur];
    const unsigned short* Bbc = Bbuf[cur];
    const int kt2 = (t + 2) & (NT - 1);  // wrap-stage (harmless, uniform counts)
    s16x8 a0[8], a1[8], b0[4], b1[4];

    // ---- phase 0: read kk0 (12 ds_read_b128) ----
#pragma unroll
    for (int i = 0; i < 8; ++i) {
      const int row = wm * 128 + i * 16 + opr;
      a0[i] = *(const s16x8*)((const char*)Abc + row * 128 + (opk2 ^ ((row & 7) << 4)));
    }
#pragma unroll
    for (int j = 0; j < 4; ++j) {
      const int row = wn * 64 + j * 16 + opr;
      b0[j] = *(const s16x8*)((const char*)Bbc + row * 128 + (opk2 ^ ((row & 7) << 4)));
    }
    PH_SYNC();
    __builtin_amdgcn_s_setprio(1);
#pragma unroll
    for (int i = 0; i < 4; ++i)
#pragma unroll
      for (int j = 0; j < 4; ++j) acc[i][j] = MFMA16(a0[i], b0[j], acc[i][j]);
    __builtin_amdgcn_s_setprio(0);
    __builtin_amdgcn_s_barrier();

    // ---- phase 1: read kk1 A (8) ----
#pragma unroll
    for (int i = 0; i < 8; ++i) {
      const int row = wm * 128 + i * 16 + opr;
      a1[i] = *(const s16x8*)((const char*)Abc + row * 128 + ((64 + opk2) ^ ((row & 7) << 4)));
    }
    PH_SYNC();
    __builtin_amdgcn_s_setprio(1);
#pragma unroll
    for (int i = 4; i < 8; ++i)
#pragma unroll
      for (int j = 0; j < 4; ++j) acc[i][j] = MFMA16(a0[i], b0[j], acc[i][j]);
    __builtin_amdgcn_s_setprio(0);
    __builtin_amdgcn_s_barrier();

    // ---- phase 2: read kk1 B (4); stage A(t+2) (A fully read after ph1) ----
#pragma unroll
    for (int j = 0; j < 4; ++j) {
      const int row = wn * 64 + j * 16 + opr;
      b1[j] = *(const s16x8*)((const char*)Bbc + row * 128 + ((64 + opk2) ^ ((row & 7) << 4)));
    }
    stageA(cur, kt2);
    PH_SYNC();
    __builtin_amdgcn_s_setprio(1);
#pragma unroll
    for (int i = 0; i < 4; ++i)
#pragma unroll
      for (int j = 0; j < 4; ++j) acc[i][j] = MFMA16(a1[i], b1[j], acc[i][j]);
    __builtin_amdgcn_s_setprio(0);
    __builtin_amdgcn_s_barrier();

    // ---- phase 3: stage B(t+2) (B fully read after ph2); boundary vmcnt(8) ----
    stageB(cur, kt2);
    __builtin_amdgcn_s_barrier();
    __builtin_amdgcn_s_setprio(1);
#pragma unroll
    for (int i = 4; i < 8; ++i)
#pragma unroll
      for (int j = 0; j < 4; ++j) acc[i][j] = MFMA16(a1[i], b1[j], acc[i][j]);
    __builtin_amdgcn_s_setprio(0);
    asm volatile("s_waitcnt vmcnt(8)" ::: "memory");  // tile t+1's loads landed
    __builtin_amdgcn_s_barrier();
  }
#undef PH_SYNC

  // ---- epilogue: C/D layout col=lane&15, row=(lane>>4)*4+reg ----
  const int cm = (lane >> 4) << 2;
  const int cn = lane & 15;
#pragma unroll
  for (int i = 0; i < 8; ++i)
#pragma unroll
    for (int j = 0; j < 4; ++j) {
      const int row = tm * 256 + wm * 128 + i * 16 + cm;
      const int col = tn * 256 + wn * 64 + j * 16 + cn;
#pragma unroll
      for (int r = 0; r < 4; ++r) {
        float v = acc[i][j][r];
        if (bf16out) Cb[(size_t)(row + r) * N + col] = f2bf(v);
        else         Cf[(size_t)(row + r) * N + col] = v;
      }
    }
}

// ---------------- bf16 transpose: out[C][R] = in[R][C]^T (in rows strided) ----------------
__global__ __launch_bounds__(256) void transpose_k(const unsigned short* __restrict__ in,
                                                   unsigned short* __restrict__ out,
                                                   int R, int C, int istride) {
  __shared__ unsigned short T[64][68];
  const int tid = threadIdx.x;
  const int nbc = C >> 6;
  const int br = blockIdx.x / nbc;
  const int bc = blockIdx.x % nbc;
  const int r0 = br << 6, c0 = bc << 6;
#pragma unroll
  for (int i = 0; i < 4; ++i) {
    int row = i * 16 + (tid >> 4);
    int col = (tid & 15) << 2;
    *(ushort4*)&T[row][col] = *(const ushort4*)(in + (size_t)(r0 + row) * istride + c0 + col);
  }
  __syncthreads();
#pragma unroll
  for (int i = 0; i < 4; ++i) {
    int row = i * 16 + (tid >> 4);
    int col = (tid & 15) << 2;
    ushort4 v;
    v.x = T[col + 0][row]; v.y = T[col + 1][row];
    v.z = T[col + 2][row]; v.w = T[col + 3][row];
    *(ushort4*)(out + (size_t)(c0 + row) * R + r0 + col) = v;
  }
}

// ---------------- RoPE cos/sin table: tab[s*64+d] = (cos, sin) ----------------
__global__ __launch_bounds__(256) void rope_tab_k(const float* __restrict__ freqs,
                                                  const int* __restrict__ pos,
                                                  float2* __restrict__ tab) {
  int i = blockIdx.x * 256 + threadIdx.x;  // S*64 = 131072
  int s = i >> 6, d = i & 63;
  float ang = freqs[((size_t)(pos[0] + s) << 6) + d];
  float sv, cv;
  sincosf(ang, &sv, &cv);
  tab[i] = make_float2(cv, sv);
}

// ---------------- RoPE apply, in-place on merged qkv buffer (row stride QKVN) ----------------
__global__ __launch_bounds__(256) void rope_k(unsigned short* __restrict__ qkv,
                                              const float2* __restrict__ tab) {
  int idx = blockIdx.x * 256 + threadIdx.x;  // 4096 * 40 * 64
  int d2 = idx & 63;
  int t = idx >> 6;
  int hh = t % (NH + NKV);
  int row = t / (NH + NKV);
  int s = row & (S_LEN - 1);
  float2 cs = tab[(s << 6) + d2];
  unsigned short* p = qkv + (size_t)row * QKVN +
                      (hh < NH ? hh * HD : DMODEL + (hh - NH) * HD) + (d2 << 1);
  unsigned int xy = *(unsigned int*)p;
  float x1 = bf2f((unsigned short)(xy & 0xffffu));
  float x2 = bf2f((unsigned short)(xy >> 16));
  float o1 = x1 * cs.x - x2 * cs.y;
  float o2 = x1 * cs.y + x2 * cs.x;
  *(unsigned int*)p = (unsigned int)f2bf(o1) | ((unsigned int)f2bf(o2) << 16);
}

// ---------------- MFMA flash attention — ROUND-5 VERIFIED (unchanged) ----------------
__global__ __launch_bounds__(256) void attn_mfma(const unsigned short* __restrict__ qb,
                                                 const unsigned short* __restrict__ kb,
                                                 const unsigned short* __restrict__ vtb,
                                                 unsigned short* __restrict__ aob) {
  __shared__ alignas(16) unsigned short Ks[64 * 128];    // 16 KB (swizzled)
  __shared__ alignas(16) unsigned short Vts[128 * 64];   // 16 KB (swizzled)
  __shared__ alignas(16) unsigned short Ps[4][16 * 72];  // 9 KB
  const int tid = threadIdx.x;
  const int lane = tid & 63;
  const int w = tid >> 6;
  const int qc = blockIdx.x & 31;        // 32 q-chunks of 64 rows
  const int bh = blockIdx.x >> 5;
  const int h = bh & 31;
  const int b = bh >> 5;
  const int kv = h >> 2;

  const int opr = lane & 15;             // operand row within 16
  const int opk2 = (lane >> 4) << 4;     // k-subblock byte offset: 0,16,32,48
  const int cm = (lane >> 4) << 2;       // C row base
  const int cn = lane & 15;              // C col

  // ---- stage Q tile (64x128) into Ks (swizzled), hoist a-frags to regs ----
  {
    const size_t qrow0 = (size_t)(b * S_LEN + qc * 64);
#pragma unroll
    for (int i = 0; i < 4; ++i) {
      int d = i * 4096 + tid * 16;
      int row = d >> 8;
      int colb = (d & 255) ^ ((row & 7) << 4);
      GLDS16(qb + (qrow0 + row) * QKVN + h * HD + (colb >> 1), (char*)Ks + d);
    }
  }
  __syncthreads();
  s16x8 aq[4];
  {
    int qrow = w * 16 + opr;
    const char* base = (const char*)Ks + qrow * 256;
#pragma unroll
    for (int kk = 0; kk < 4; ++kk)
      aq[kk] = *(const s16x8*)(base + ((kk * 64 + opk2) ^ ((qrow & 7) << 4)));
  }

  float m_run[4], l_run[4];
  fx4 acc_o[8] = {};
#pragma unroll
  for (int r = 0; r < 4; ++r) { m_run[r] = -1e30f; l_run[r] = 0.f; }
  const float scale = 0.08838834764831845f;  // 1/sqrt(128)
  unsigned short* Pw = Ps[w];

  for (int t0 = 0; t0 < S_LEN; t0 += 64) {
    __syncthreads();  // prev-tile LDS reads done (covers Q-frag reads on iter 0)
    const size_t krow0 = (size_t)(b * S_LEN + t0);
#pragma unroll
    for (int i = 0; i < 4; ++i) {  // K tile [64][128]
      int d = i * 4096 + tid * 16;
      int row = d >> 8;
      int colb = (d & 255) ^ ((row & 7) << 4);
      GLDS16(kb + (krow0 + row) * QKVN + kv * HD + (colb >> 1), (char*)Ks + d);
    }
#pragma unroll
    for (int i = 0; i < 4; ++i) {  // V^T tile [128][64]
      int d = i * 4096 + tid * 16;
      int row = d >> 7;
      int colb = (d & 127) ^ ((row & 7) << 4);
      GLDS16(vtb + (size_t)(kv * HD + row) * MROWS + (size_t)(b * S_LEN + t0) + (colb >> 1),
             (char*)Vts + d);
    }
    __syncthreads();  // staged data visible (barrier drains vmcnt)

    // ---- QK^T: accs[jb] = Q(16) x K(16)^T over K=128 ----
    fx4 accs[4] = {};
#pragma unroll
    for (int jb = 0; jb < 4; ++jb) {
      int krow = jb * 16 + opr;
      const char* kbase = (const char*)Ks + krow * 256;
#pragma unroll
      for (int kk = 0; kk < 4; ++kk) {
        s16x8 bk = *(const s16x8*)(kbase + ((kk * 64 + opk2) ^ ((krow & 7) << 4)));
        accs[jb] = MFMA16(aq[kk], bk, accs[jb]);
      }
    }

    // ---- online softmax over this tile's 64 keys (rows = cm+reg) ----
    float p[4][4];       // [jb][reg]
    float mloc[4], psum[4], alpha[4];
#pragma unroll
    for (int r = 0; r < 4; ++r) {
      float a0 = accs[0][r] * scale, a1 = accs[1][r] * scale;
      float a2 = accs[2][r] * scale, a3 = accs[3][r] * scale;
      p[0][r] = a0; p[1][r] = a1; p[2][r] = a2; p[3][r] = a3;
      mloc[r] = fmaxf(fmaxf(a0, a1), fmaxf(a2, a3));
    }
#pragma unroll
    for (int off = 1; off <= 8; off <<= 1)
#pragma unroll
      for (int r = 0; r < 4; ++r) mloc[r] = fmaxf(mloc[r], __shfl_xor(mloc[r], off));
#pragma unroll
    for (int r = 0; r < 4; ++r) {
      float mnew = fmaxf(m_run[r], mloc[r]);
      alpha[r] = __expf(m_run[r] - mnew);
      m_run[r] = mnew;
      psum[r] = 0.f;
#pragma unroll
      for (int jb = 0; jb < 4; ++jb) {
        p[jb][r] = __expf(p[jb][r] - mnew);
        psum[r] += p[jb][r];
      }
    }
#pragma unroll
    for (int off = 1; off <= 8; off <<= 1)
#pragma unroll
      for (int r = 0; r < 4; ++r) psum[r] += __shfl_xor(psum[r], off);
#pragma unroll
    for (int r = 0; r < 4; ++r) l_run[r] = l_run[r] * alpha[r] + psum[r];
#pragma unroll
    for (int db = 0; db < 8; ++db)
#pragma unroll
      for (int r = 0; r < 4; ++r) acc_o[db][r] *= alpha[r];

    // ---- P (bf16) -> wave-private LDS, reload as A-frags ----
#pragma unroll
    for (int jb = 0; jb < 4; ++jb)
#pragma unroll
      for (int r = 0; r < 4; ++r)
        Pw[(cm + r) * 72 + jb * 16 + cn] = f2bf(p[jb][r]);
    s16x8 ap[2];
#pragma unroll
    for (int tb = 0; tb < 2; ++tb)
      ap[tb] = *(const s16x8*)((const char*)Pw + opr * 144 + tb * 64 + opk2);

    // ---- PV: acc_o[db] += P(16x64) x V^T(16x64)^T ----
#pragma unroll
    for (int db = 0; db < 8; ++db) {
      int vrow = db * 16 + opr;
      const char* vbase = (const char*)Vts + vrow * 128;
#pragma unroll
      for (int tb = 0; tb < 2; ++tb) {
        s16x8 bv = *(const s16x8*)(vbase + ((tb * 64 + opk2) ^ ((vrow & 7) << 4)));
        acc_o[db] = MFMA16(ap[tb], bv, acc_o[db]);
      }
    }
  }

  // ---- epilogue: normalize, write bf16 ----
  float inv[4];
#pragma unroll
  for (int r = 0; r < 4; ++r) inv[r] = 1.0f / l_run[r];
#pragma unroll
  for (int db = 0; db < 8; ++db)
#pragma unroll
    for (int r = 0; r < 4; ++r) {
      size_t row = (size_t)(b * S_LEN + qc * 64 + w * 16 + cm + r);
      aob[row * DMODEL + h * HD + db * 16 + cn] = f2bf(acc_o[db][r] * inv[r]);
    }
}

// ---------------- launch ----------------
extern "C" void kernel_launch(void* const* d_in, const int* in_sizes, int n_in,
                              void* d_out, int out_size, void* d_ws, size_t ws_size,
                              hipStream_t stream) {
  const float* hs = (const float*)d_in[0];
  const float* fr = (const float*)d_in[1];
  const float* Wq = (const float*)d_in[2];
  const float* Wk = (const float*)d_in[3];
  const float* Wv = (const float*)d_in[4];
  const float* Wo = (const float*)d_in[5];
  const int* pos = (const int*)d_in[6];
  float* out = (float*)d_out;

  // workspace (bf16 elems), total 83,886,080 shorts = 167.8 MB
  unsigned short* w = (unsigned short*)d_ws;
  unsigned short* hsb   = w; w += 16777216;  // [4096,4096] hs bf16 (tab reuses after QKV gemm)
  unsigned short* wqkvb = w; w += 25165824;  // [6144,4096] Wq|Wk|Wv  (aob+vtb reuse after gemm)
  unsigned short* wob   = w; w += 16777216;  // [4096,4096]
  unsigned short* qkvb  = w; w += 25165824;  // [4096,6144] q|k|v per row (rope in-place)
  unsigned short* aob = wqkvb;               // [4096,4096] attn out
  unsigned short* vtb = wqkvb + 16777216;    // [1024,4096] V^T
  float2* tab = (float2*)hsb;                // [2048*64] cos/sin

  if (ws_size < (size_t)83886080 * 2) return;

  cast_all_k<<<57344, 256, 0, stream>>>(hs, Wq, Wk, Wv, Wo, hsb, wqkvb, wob);

  // fused QKV projection: [4096,4096] x [6144,4096]^T -> [4096,6144]
  gemm256<<<384, 512, 0, stream>>>(hsb, wqkvb, nullptr, qkvb, MROWS, QKVN, DMODEL, 1);

  rope_tab_k<<<512, 256, 0, stream>>>(fr, pos, tab);   // hsb dead now
  rope_k<<<40960, 256, 0, stream>>>(qkvb, tab);

  transpose_k<<<1024, 256, 0, stream>>>(qkvb + 5120, vtb, MROWS, 1024, QKVN);  // V -> V^T

  attn_mfma<<<2048, 256, 0, stream>>>(qkvb, qkvb + 4096, vtb, aob);

  // output projection: [4096,4096] x [4096,4096]^T -> f32 out
  gemm256<<<256, 512, 0, stream>>>(aob, wob, out, nullptr, MROWS, DMODEL, DMODEL, 0);
}

// Round 8
// 629.202 us; speedup vs baseline: 1.8026x; 1.1919x over previous
//
#include <hip/hip_runtime.h>

// ---------------- constants ----------------
#define S_LEN 2048
#define NH 32
#define NKV 8
#define HD 128
#define DMODEL 4096
#define MROWS 4096   // B*S
#define QKVN 6144    // 4096 q + 1024 k + 1024 v output cols

typedef short s16x8 __attribute__((ext_vector_type(8)));
typedef float fx4 __attribute__((ext_vector_type(4)));

__device__ __forceinline__ unsigned short f2bf(float f) {
  unsigned int u = __float_as_uint(f);
  u += 0x7fffu + ((u >> 16) & 1u);   // round-to-nearest-even
  return (unsigned short)(u >> 16);
}
__device__ __forceinline__ float bf2f(unsigned short h) {
  return __uint_as_float(((unsigned int)h) << 16);
}

#define GLDS16(gp, lp)                                                        \
  __builtin_amdgcn_global_load_lds(                                           \
      (const __attribute__((address_space(1))) void*)(gp),                    \
      (__attribute__((address_space(3))) void*)(lp), 16, 0, 0)

#define MFMA16(a, b, c) __builtin_amdgcn_mfma_f32_16x16x32_bf16((a), (b), (c), 0, 0, 0)

// ---------------- fused f32 -> bf16 casts (all 5 tensors, one launch) ----------------
__global__ __launch_bounds__(256) void cast_all_k(const float* __restrict__ hs,
                                                  const float* __restrict__ Wq,
                                                  const float* __restrict__ Wk,
                                                  const float* __restrict__ Wv,
                                                  const float* __restrict__ Wo,
                                                  unsigned short* __restrict__ hsb,
                                                  unsigned short* __restrict__ wqkvb,
                                                  unsigned short* __restrict__ wob) {
  int i = blockIdx.x * 256 + threadIdx.x;
  const float* src;
  unsigned short* dst;
  int off;
  if (i < 4194304)       { src = hs; dst = hsb;                off = 0; }
  else if (i < 8388608)  { src = Wq; dst = wqkvb;              off = 4194304; }
  else if (i < 9437184)  { src = Wk; dst = wqkvb + 16777216;   off = 8388608; }
  else if (i < 10485760) { src = Wv; dst = wqkvb + 20971520;   off = 9437184; }
  else                   { src = Wo; dst = wob;                off = 10485760; }
  int j = i - off;
  float4 v = *(const float4*)(src + (size_t)j * 4);
  ushort4 o;
  o.x = f2bf(v.x); o.y = f2bf(v.y); o.z = f2bf(v.z); o.w = f2bf(v.w);
  *(ushort4*)(dst + (size_t)j * 4) = o;
}

// ---------------- 256x256 8-phase bf16 GEMM (R7-verified) ----------------
__global__ __launch_bounds__(512, 2) void gemm256(const unsigned short* __restrict__ A,
                                                  const unsigned short* __restrict__ Bt,
                                                  float* __restrict__ Cf,
                                                  unsigned short* __restrict__ Cb,
                                                  int M, int N, int K, int bf16out) {
  __shared__ unsigned short Abuf[2][16384];  // [2][256 rows][64 cols]
  __shared__ unsigned short Bbuf[2][16384];
  const int tid = threadIdx.x;
  const int lane = tid & 63;
  const int w = tid >> 6;
  const int wm = w >> 2;   // 0..1
  const int wn = w & 3;    // 0..3

  const int nwg = gridDim.x;
  const int wg = (blockIdx.x & 7) * (nwg >> 3) + (blockIdx.x >> 3);  // XCD swizzle
  const int ntn = N >> 8;
  const int tm = wg / ntn;
  const int tn = wg % ntn;

  const int opr = lane & 15;
  const int opk2 = (lane >> 4) << 4;   // byte offset {0,16,32,48}
  const int NT = K >> 6;

  const unsigned short* Agbase = A + (size_t)(tm * 256) * K;
  const unsigned short* Bgbase = Bt + (size_t)(tn * 256) * K;
  const int abase = wm * 16384 + wn * 4096;
  const int bbase = (wn >> 1) * 16384 + (wm * 2 + (wn & 1)) * 4096;

  auto stageA = [&](int bsel, int kt) {
#pragma unroll
    for (int r = 0; r < 4; ++r) {
      const int d = abase + r * 1024 + lane * 16;
      const int row = d >> 7;
      const int u = (d & 127) ^ ((row & 7) << 4);
      GLDS16(Agbase + (size_t)row * K + kt * 64 + (u >> 1), (char*)&Abuf[bsel][0] + d);
    }
  };
  auto stageB = [&](int bsel, int kt) {
#pragma unroll
    for (int r = 0; r < 4; ++r) {
      const int d = bbase + r * 1024 + lane * 16;
      const int row = d >> 7;
      const int u = (d & 127) ^ ((row & 7) << 4);
      GLDS16(Bgbase + (size_t)row * K + kt * 64 + (u >> 1), (char*)&Bbuf[bsel][0] + d);
    }
  };

  fx4 acc[8][4] = {};

  stageA(0, 0); stageB(0, 0);
  stageA(1, 1); stageB(1, 1);
  asm volatile("s_waitcnt vmcnt(8)" ::: "memory");
  __builtin_amdgcn_s_barrier();

#define PH_SYNC()                                            \
  do {                                                       \
    __builtin_amdgcn_s_barrier();                            \
    asm volatile("s_waitcnt lgkmcnt(0)" ::: "memory");       \
    __builtin_amdgcn_sched_barrier(0);                       \
  } while (0)

#pragma unroll 1
  for (int t = 0; t < NT; ++t) {
    const int cur = t & 1;
    const unsigned short* Abc = Abuf[cur];
    const unsigned short* Bbc = Bbuf[cur];
    const int kt2 = (t + 2) & (NT - 1);
    s16x8 a0[8], a1[8], b0[4], b1[4];

#pragma unroll
    for (int i = 0; i < 8; ++i) {
      const int row = wm * 128 + i * 16 + opr;
      a0[i] = *(const s16x8*)((const char*)Abc + row * 128 + (opk2 ^ ((row & 7) << 4)));
    }
#pragma unroll
    for (int j = 0; j < 4; ++j) {
      const int row = wn * 64 + j * 16 + opr;
      b0[j] = *(const s16x8*)((const char*)Bbc + row * 128 + (opk2 ^ ((row & 7) << 4)));
    }
    PH_SYNC();
    __builtin_amdgcn_s_setprio(1);
#pragma unroll
    for (int i = 0; i < 4; ++i)
#pragma unroll
      for (int j = 0; j < 4; ++j) acc[i][j] = MFMA16(a0[i], b0[j], acc[i][j]);
    __builtin_amdgcn_s_setprio(0);
    __builtin_amdgcn_s_barrier();

#pragma unroll
    for (int i = 0; i < 8; ++i) {
      const int row = wm * 128 + i * 16 + opr;
      a1[i] = *(const s16x8*)((const char*)Abc + row * 128 + ((64 + opk2) ^ ((row & 7) << 4)));
    }
    PH_SYNC();
    __builtin_amdgcn_s_setprio(1);
#pragma unroll
    for (int i = 4; i < 8; ++i)
#pragma unroll
      for (int j = 0; j < 4; ++j) acc[i][j] = MFMA16(a0[i], b0[j], acc[i][j]);
    __builtin_amdgcn_s_setprio(0);
    __builtin_amdgcn_s_barrier();

#pragma unroll
    for (int j = 0; j < 4; ++j) {
      const int row = wn * 64 + j * 16 + opr;
      b1[j] = *(const s16x8*)((const char*)Bbc + row * 128 + ((64 + opk2) ^ ((row & 7) << 4)));
    }
    stageA(cur, kt2);
    PH_SYNC();
    __builtin_amdgcn_s_setprio(1);
#pragma unroll
    for (int i = 0; i < 4; ++i)
#pragma unroll
      for (int j = 0; j < 4; ++j) acc[i][j] = MFMA16(a1[i], b1[j], acc[i][j]);
    __builtin_amdgcn_s_setprio(0);
    __builtin_amdgcn_s_barrier();

    stageB(cur, kt2);
    __builtin_amdgcn_s_barrier();
    __builtin_amdgcn_s_setprio(1);
#pragma unroll
    for (int i = 4; i < 8; ++i)
#pragma unroll
      for (int j = 0; j < 4; ++j) acc[i][j] = MFMA16(a1[i], b1[j], acc[i][j]);
    __builtin_amdgcn_s_setprio(0);
    asm volatile("s_waitcnt vmcnt(8)" ::: "memory");
    __builtin_amdgcn_s_barrier();
  }
#undef PH_SYNC

  const int cm = (lane >> 4) << 2;
  const int cn = lane & 15;
#pragma unroll
  for (int i = 0; i < 8; ++i)
#pragma unroll
    for (int j = 0; j < 4; ++j) {
      const int row = tm * 256 + wm * 128 + i * 16 + cm;
      const int col = tn * 256 + wn * 64 + j * 16 + cn;
#pragma unroll
      for (int r = 0; r < 4; ++r) {
        float v = acc[i][j][r];
        if (bf16out) Cb[(size_t)(row + r) * N + col] = f2bf(v);
        else         Cf[(size_t)(row + r) * N + col] = v;
      }
    }
}

// ---------------- bf16 transpose: out[C][R] = in[R][C]^T (in rows strided) ----------------
__global__ __launch_bounds__(256) void transpose_k(const unsigned short* __restrict__ in,
                                                   unsigned short* __restrict__ out,
                                                   int R, int C, int istride) {
  __shared__ unsigned short T[64][68];
  const int tid = threadIdx.x;
  const int nbc = C >> 6;
  const int br = blockIdx.x / nbc;
  const int bc = blockIdx.x % nbc;
  const int r0 = br << 6, c0 = bc << 6;
#pragma unroll
  for (int i = 0; i < 4; ++i) {
    int row = i * 16 + (tid >> 4);
    int col = (tid & 15) << 2;
    *(ushort4*)&T[row][col] = *(const ushort4*)(in + (size_t)(r0 + row) * istride + c0 + col);
  }
  __syncthreads();
#pragma unroll
  for (int i = 0; i < 4; ++i) {
    int row = i * 16 + (tid >> 4);
    int col = (tid & 15) << 2;
    ushort4 v;
    v.x = T[col + 0][row]; v.y = T[col + 1][row];
    v.z = T[col + 2][row]; v.w = T[col + 3][row];
    *(ushort4*)(out + (size_t)(c0 + row) * R + r0 + col) = v;
  }
}

// ---------------- RoPE cos/sin table ----------------
__global__ __launch_bounds__(256) void rope_tab_k(const float* __restrict__ freqs,
                                                  const int* __restrict__ pos,
                                                  float2* __restrict__ tab) {
  int i = blockIdx.x * 256 + threadIdx.x;  // S*64 = 131072
  int s = i >> 6, d = i & 63;
  float ang = freqs[((size_t)(pos[0] + s) << 6) + d];
  float sv, cv;
  sincosf(ang, &sv, &cv);
  tab[i] = make_float2(cv, sv);
}

// ---------------- RoPE apply, in-place on merged qkv buffer ----------------
__global__ __launch_bounds__(256) void rope_k(unsigned short* __restrict__ qkv,
                                              const float2* __restrict__ tab) {
  int idx = blockIdx.x * 256 + threadIdx.x;  // 4096 * 40 * 64
  int d2 = idx & 63;
  int t = idx >> 6;
  int hh = t % (NH + NKV);
  int row = t / (NH + NKV);
  int s = row & (S_LEN - 1);
  float2 cs = tab[(s << 6) + d2];
  unsigned short* p = qkv + (size_t)row * QKVN +
                      (hh < NH ? hh * HD : DMODEL + (hh - NH) * HD) + (d2 << 1);
  unsigned int xy = *(unsigned int*)p;
  float x1 = bf2f((unsigned short)(xy & 0xffffu));
  float x2 = bf2f((unsigned short)(xy >> 16));
  float o1 = x1 * cs.x - x2 * cs.y;
  float o2 = x1 * cs.y + x2 * cs.x;
  *(unsigned int*)p = (unsigned int)f2bf(o1) | ((unsigned int)f2bf(o2) << 16);
}

// ---------------- MFMA flash attention: R6 compute structure + R5 LDS staging ----------------
// 4 waves/block; block owns (b, h, 128 q-rows); wave owns 32. K-tile = 64 keys.
// S^T = MFMA(K-frag, Q-frag): softmax columns lane-local (q = cn), 2 shfl/qb.
// K[64][128] and V^T[128][64] staged swizzled via global_load_lds (R5 verbatim);
// frag reads from LDS (R5's verified bk/bv patterns). P path wave-private LDS
// (R6 verbatim). Q-frags hoisted once from global (R6 verbatim).
__global__ __launch_bounds__(256, 2) void attn_mfma(const unsigned short* __restrict__ qkv,
                                                    const unsigned short* __restrict__ vtb,
                                                    unsigned short* __restrict__ aob) {
  __shared__ alignas(16) unsigned short Ks[64 * 128];    // 16 KB (swizzled)
  __shared__ alignas(16) unsigned short Vts[128 * 64];   // 16 KB (swizzled)
  __shared__ alignas(16) unsigned short Ps[4][32 * 72];  // 18 KB
  const int tid = threadIdx.x;
  const int lane = tid & 63;
  const int w = tid >> 6;
  // chunked XCD swizzle: each XCD gets 128 consecutive lg = 2 (b,kvi) K/V sets
  const int lg = (blockIdx.x & 7) * 128 + (blockIdx.x >> 3);  // grid = 1024
  const int qc = lg & 15;            // 16 q-chunks of 128 rows
  const int hsub = (lg >> 4) & 3;
  const int kvi = (lg >> 6) & 7;
  const int b = lg >> 9;
  const int h = kvi * 4 + hsub;

  const int opr = lane & 15;         // operand row within 16
  const int g = lane >> 4;           // k-subblock 0..3
  const int ak = g * 8;              // operand k offset (shorts)
  const int opk2 = g * 16;           // operand k offset (bytes)
  const int cm = g * 4;              // C/D row base
  const int cn = opr;                // C/D col

  const int qrow0 = b * S_LEN + qc * 128 + w * 32;
  unsigned short* Pw = Ps[w];

  // ---- Q b-frags hoisted once from global (R6-verified) ----
  s16x8 qf[2][4];
#pragma unroll
  for (int qb = 0; qb < 2; ++qb)
#pragma unroll
    for (int kk = 0; kk < 4; ++kk)
      qf[qb][kk] = *(const s16x8*)(qkv + (size_t)(qrow0 + qb * 16 + opr) * QKVN +
                                   h * HD + kk * 32 + ak);

  float m_run[2] = {-1e30f, -1e30f};
  float l_run[2] = {0.f, 0.f};
  fx4 acc[8][2] = {};
  const float scale = 0.08838834764831845f;  // 1/sqrt(128)

  for (int t0 = 0; t0 < S_LEN; t0 += 64) {
    __syncthreads();  // prev tile's LDS reads complete
    const size_t krow0 = (size_t)(b * S_LEN + t0);
#pragma unroll
    for (int i = 0; i < 4; ++i) {  // K tile [64][128] (R5 staging verbatim)
      int d = i * 4096 + tid * 16;
      int row = d >> 8;
      int colb = (d & 255) ^ ((row & 7) << 4);
      GLDS16(qkv + (krow0 + row) * QKVN + DMODEL + kvi * HD + (colb >> 1), (char*)Ks + d);
    }
#pragma unroll
    for (int i = 0; i < 4; ++i) {  // V^T tile [128][64] (R5 staging verbatim)
      int d = i * 4096 + tid * 16;
      int row = d >> 7;
      int colb = (d & 127) ^ ((row & 7) << 4);
      GLDS16(vtb + (size_t)(kvi * HD + row) * MROWS + (size_t)(b * S_LEN + t0) + (colb >> 1),
             (char*)Vts + d);
    }
    __syncthreads();  // staged data visible (barrier drains vmcnt)

    // ---- S^T[key][q] = MFMA(K-frag, Q-frag) over d=128 ----
    fx4 st[4][2] = {};
#pragma unroll
    for (int kb2 = 0; kb2 < 4; ++kb2) {
      int krow = kb2 * 16 + opr;
      const char* kbase = (const char*)Ks + krow * 256;
      s16x8 kf[4];
#pragma unroll
      for (int kk = 0; kk < 4; ++kk)
        kf[kk] = *(const s16x8*)(kbase + ((kk * 64 + opk2) ^ ((krow & 7) << 4)));
#pragma unroll
      for (int qb = 0; qb < 2; ++qb)
#pragma unroll
        for (int kk = 0; kk < 4; ++kk)
          st[kb2][qb] = MFMA16(kf[kk], qf[qb][kk], st[kb2][qb]);
    }

    // ---- softmax per q-column (R6 verbatim) ----
    float mloc[2], alpha[2], psum[2];
#pragma unroll
    for (int qb = 0; qb < 2; ++qb) {
      float mm = -1e30f;
#pragma unroll
      for (int kb2 = 0; kb2 < 4; ++kb2)
#pragma unroll
        for (int r = 0; r < 4; ++r) mm = fmaxf(mm, st[kb2][qb][r] * scale);
      mm = fmaxf(mm, __shfl_xor(mm, 16));
      mm = fmaxf(mm, __shfl_xor(mm, 32));
      mloc[qb] = mm;
      float mnew = fmaxf(m_run[qb], mm);
      alpha[qb] = __expf(m_run[qb] - mnew);   // first tile: exp(-huge) = 0
      m_run[qb] = mnew;
      psum[qb] = 0.f;
    }
#pragma unroll
    for (int db = 0; db < 8; ++db)
#pragma unroll
      for (int qb = 0; qb < 2; ++qb)
#pragma unroll
        for (int r = 0; r < 4; ++r) acc[db][qb][r] *= alpha[qb];

#pragma unroll
    for (int kb2 = 0; kb2 < 4; ++kb2)
#pragma unroll
      for (int qb = 0; qb < 2; ++qb)
#pragma unroll
        for (int r = 0; r < 4; ++r) {
          float pv = __expf(st[kb2][qb][r] * scale - m_run[qb]);
          psum[qb] += pv;
          Pw[(qb * 16 + cn) * 72 + kb2 * 16 + cm + r] = f2bf(pv);
        }
#pragma unroll
    for (int qb = 0; qb < 2; ++qb) {
      float s = psum[qb];
      s += __shfl_xor(s, 16);
      s += __shfl_xor(s, 32);
      l_run[qb] = l_run[qb] * alpha[qb] + s;
    }

    // ---- P b-frags (wave-private LDS, in-order within wave) ----
    s16x8 pf[2][2];
#pragma unroll
    for (int qb = 0; qb < 2; ++qb)
#pragma unroll
      for (int tb = 0; tb < 2; ++tb)
        pf[qb][tb] = *(const s16x8*)(Pw + (qb * 16 + opr) * 72 + tb * 32 + ak);

    // ---- O^T += MFMA(V^T-frag, P-frag) over t=64 (V^T frags from LDS) ----
#pragma unroll
    for (int db = 0; db < 8; ++db) {
      int vrow = db * 16 + opr;
      const char* vbase = (const char*)Vts + vrow * 128;
      s16x8 vf[2];
#pragma unroll
      for (int tb = 0; tb < 2; ++tb)
        vf[tb] = *(const s16x8*)(vbase + ((tb * 64 + opk2) ^ ((vrow & 7) << 4)));
#pragma unroll
      for (int qb = 0; qb < 2; ++qb)
#pragma unroll
        for (int tb = 0; tb < 2; ++tb)
          acc[db][qb] = MFMA16(vf[tb], pf[qb][tb], acc[db][qb]);
    }
  }

  // ---- epilogue (R6 verbatim): normalize per q, pack 4 consecutive d -> 8B ----
  float inv[2] = {1.0f / l_run[0], 1.0f / l_run[1]};
#pragma unroll
  for (int db = 0; db < 8; ++db)
#pragma unroll
    for (int qb = 0; qb < 2; ++qb) {
      ushort4 o;
      o.x = f2bf(acc[db][qb][0] * inv[qb]);
      o.y = f2bf(acc[db][qb][1] * inv[qb]);
      o.z = f2bf(acc[db][qb][2] * inv[qb]);
      o.w = f2bf(acc[db][qb][3] * inv[qb]);
      *(ushort4*)(aob + (size_t)(qrow0 + qb * 16 + cn) * DMODEL + h * HD + db * 16 + cm) = o;
    }
}

// ---------------- launch ----------------
extern "C" void kernel_launch(void* const* d_in, const int* in_sizes, int n_in,
                              void* d_out, int out_size, void* d_ws, size_t ws_size,
                              hipStream_t stream) {
  const float* hs = (const float*)d_in[0];
  const float* fr = (const float*)d_in[1];
  const float* Wq = (const float*)d_in[2];
  const float* Wk = (const float*)d_in[3];
  const float* Wv = (const float*)d_in[4];
  const float* Wo = (const float*)d_in[5];
  const int* pos = (const int*)d_in[6];
  float* out = (float*)d_out;

  // workspace (bf16 elems), total 83,886,080 shorts = 167.8 MB
  unsigned short* w = (unsigned short*)d_ws;
  unsigned short* hsb   = w; w += 16777216;  // [4096,4096] hs bf16 (tab reuses after QKV gemm)
  unsigned short* wqkvb = w; w += 25165824;  // [6144,4096] Wq|Wk|Wv  (aob+vtb reuse after gemm)
  unsigned short* wob   = w; w += 16777216;  // [4096,4096]
  unsigned short* qkvb  = w; w += 25165824;  // [4096,6144] q|k|v per row (rope in-place)
  unsigned short* aob = wqkvb;               // [4096,4096] attn out
  unsigned short* vtb = wqkvb + 16777216;    // [1024,4096] V^T
  float2* tab = (float2*)hsb;                // [2048*64] cos/sin

  if (ws_size < (size_t)83886080 * 2) return;

  cast_all_k<<<57344, 256, 0, stream>>>(hs, Wq, Wk, Wv, Wo, hsb, wqkvb, wob);

  // fused QKV projection: [4096,4096] x [6144,4096]^T -> [4096,6144]
  gemm256<<<384, 512, 0, stream>>>(hsb, wqkvb, nullptr, qkvb, MROWS, QKVN, DMODEL, 1);

  rope_tab_k<<<512, 256, 0, stream>>>(fr, pos, tab);   // hsb dead now
  rope_k<<<40960, 256, 0, stream>>>(qkvb, tab);

  transpose_k<<<1024, 256, 0, stream>>>(qkvb + 5120, vtb, MROWS, 1024, QKVN);  // V -> V^T

  attn_mfma<<<1024, 256, 0, stream>>>(qkvb, vtb, aob);

  // output projection: [4096,4096] x [4096,4096]^T -> f32 out
  gemm256<<<256, 512, 0, stream>>>(aob, wob, out, nullptr, MROWS, DMODEL, DMODEL, 0);
}

// Round 9
// 616.519 us; speedup vs baseline: 1.8397x; 1.0206x over previous
//
#include <hip/hip_runtime.h>

// ---------------- constants ----------------
#define S_LEN 2048
#define NH 32
#define NKV 8
#define HD 128
#define DMODEL 4096
#define MROWS 4096   // B*S
#define QKVN 6144    // 4096 q + 1024 k + 1024 v output cols

typedef short s16x8 __attribute__((ext_vector_type(8)));
typedef float fx4 __attribute__((ext_vector_type(4)));

__device__ __forceinline__ unsigned short f2bf(float f) {
  unsigned int u = __float_as_uint(f);
  u += 0x7fffu + ((u >> 16) & 1u);   // round-to-nearest-even
  return (unsigned short)(u >> 16);
}
__device__ __forceinline__ float bf2f(unsigned short h) {
  return __uint_as_float(((unsigned int)h) << 16);
}

#define GLDS16(gp, lp)                                                        \
  __builtin_amdgcn_global_load_lds(                                           \
      (const __attribute__((address_space(1))) void*)(gp),                    \
      (__attribute__((address_space(3))) void*)(lp), 16, 0, 0)

#define MFMA16(a, b, c) __builtin_amdgcn_mfma_f32_16x16x32_bf16((a), (b), (c), 0, 0, 0)

// ---------------- fused f32 -> bf16 casts (all 5 tensors, one launch) ----------------
__global__ __launch_bounds__(256) void cast_all_k(const float* __restrict__ hs,
                                                  const float* __restrict__ Wq,
                                                  const float* __restrict__ Wk,
                                                  const float* __restrict__ Wv,
                                                  const float* __restrict__ Wo,
                                                  unsigned short* __restrict__ hsb,
                                                  unsigned short* __restrict__ wqkvb,
                                                  unsigned short* __restrict__ wob) {
  int i = blockIdx.x * 256 + threadIdx.x;
  const float* src;
  unsigned short* dst;
  int off;
  if (i < 4194304)       { src = hs; dst = hsb;                off = 0; }
  else if (i < 8388608)  { src = Wq; dst = wqkvb;              off = 4194304; }
  else if (i < 9437184)  { src = Wk; dst = wqkvb + 16777216;   off = 8388608; }
  else if (i < 10485760) { src = Wv; dst = wqkvb + 20971520;   off = 9437184; }
  else                   { src = Wo; dst = wob;                off = 10485760; }
  int j = i - off;
  float4 v = *(const float4*)(src + (size_t)j * 4);
  ushort4 o;
  o.x = f2bf(v.x); o.y = f2bf(v.y); o.z = f2bf(v.z); o.w = f2bf(v.w);
  *(ushort4*)(dst + (size_t)j * 4) = o;
}

// ---------------- 256x256 8-phase bf16 GEMM (R7-verified schedule) ----------------
// R9 change (index relabel ONLY): rectangle-per-XCD tile mapping. xcd =
// blockIdx%8 (HW round-robin); each XCD owns an (nm/2)x(nn/4) rectangle of
// tiles walked column-major, so its ~32 co-resident blocks form an 8x4 patch
// sharing A-row/B-col panels in its private L2 (per-k-slice set = 384 KB).
// Requires (M>>8)%2==0, (N>>8)%4==0, grid%8==0 — true for both launches.
__global__ __launch_bounds__(512, 2) void gemm256(const unsigned short* __restrict__ A,
                                                  const unsigned short* __restrict__ Bt,
                                                  float* __restrict__ Cf,
                                                  unsigned short* __restrict__ Cb,
                                                  int M, int N, int K, int bf16out) {
  __shared__ unsigned short Abuf[2][16384];  // [2][256 rows][64 cols]
  __shared__ unsigned short Bbuf[2][16384];
  const int tid = threadIdx.x;
  const int lane = tid & 63;
  const int w = tid >> 6;
  const int wm = w >> 2;   // 0..1
  const int wn = w & 3;    // 0..3

  const int nm = M >> 8;
  const int nn = N >> 8;
  const int rh = nm >> 1;              // rectangle height (tiles)
  const int rw = nn >> 2;              // rectangle width (tiles)
  const int xcd = blockIdx.x & 7;
  const int l = blockIdx.x >> 3;       // per-XCD sequence, 0..rh*rw-1
  const int tm = (xcd >> 2) * rh + (l % rh);
  const int tn = (xcd & 3) * rw + (l / rh);

  const int opr = lane & 15;
  const int opk2 = (lane >> 4) << 4;   // byte offset {0,16,32,48}
  const int NT = K >> 6;

  const unsigned short* Agbase = A + (size_t)(tm * 256) * K;
  const unsigned short* Bgbase = Bt + (size_t)(tn * 256) * K;
  const int abase = wm * 16384 + wn * 4096;
  const int bbase = (wn >> 1) * 16384 + (wm * 2 + (wn & 1)) * 4096;

  auto stageA = [&](int bsel, int kt) {
#pragma unroll
    for (int r = 0; r < 4; ++r) {
      const int d = abase + r * 1024 + lane * 16;
      const int row = d >> 7;
      const int u = (d & 127) ^ ((row & 7) << 4);
      GLDS16(Agbase + (size_t)row * K + kt * 64 + (u >> 1), (char*)&Abuf[bsel][0] + d);
    }
  };
  auto stageB = [&](int bsel, int kt) {
#pragma unroll
    for (int r = 0; r < 4; ++r) {
      const int d = bbase + r * 1024 + lane * 16;
      const int row = d >> 7;
      const int u = (d & 127) ^ ((row & 7) << 4);
      GLDS16(Bgbase + (size_t)row * K + kt * 64 + (u >> 1), (char*)&Bbuf[bsel][0] + d);
    }
  };

  fx4 acc[8][4] = {};

  stageA(0, 0); stageB(0, 0);
  stageA(1, 1); stageB(1, 1);
  asm volatile("s_waitcnt vmcnt(8)" ::: "memory");
  __builtin_amdgcn_s_barrier();

#define PH_SYNC()                                            \
  do {                                                       \
    __builtin_amdgcn_s_barrier();                            \
    asm volatile("s_waitcnt lgkmcnt(0)" ::: "memory");       \
    __builtin_amdgcn_sched_barrier(0);                       \
  } while (0)

#pragma unroll 1
  for (int t = 0; t < NT; ++t) {
    const int cur = t & 1;
    const unsigned short* Abc = Abuf[cur];
    const unsigned short* Bbc = Bbuf[cur];
    const int kt2 = (t + 2) & (NT - 1);
    s16x8 a0[8], a1[8], b0[4], b1[4];

#pragma unroll
    for (int i = 0; i < 8; ++i) {
      const int row = wm * 128 + i * 16 + opr;
      a0[i] = *(const s16x8*)((const char*)Abc + row * 128 + (opk2 ^ ((row & 7) << 4)));
    }
#pragma unroll
    for (int j = 0; j < 4; ++j) {
      const int row = wn * 64 + j * 16 + opr;
      b0[j] = *(const s16x8*)((const char*)Bbc + row * 128 + (opk2 ^ ((row & 7) << 4)));
    }
    PH_SYNC();
    __builtin_amdgcn_s_setprio(1);
#pragma unroll
    for (int i = 0; i < 4; ++i)
#pragma unroll
      for (int j = 0; j < 4; ++j) acc[i][j] = MFMA16(a0[i], b0[j], acc[i][j]);
    __builtin_amdgcn_s_setprio(0);
    __builtin_amdgcn_s_barrier();

#pragma unroll
    for (int i = 0; i < 8; ++i) {
      const int row = wm * 128 + i * 16 + opr;
      a1[i] = *(const s16x8*)((const char*)Abc + row * 128 + ((64 + opk2) ^ ((row & 7) << 4)));
    }
    PH_SYNC();
    __builtin_amdgcn_s_setprio(1);
#pragma unroll
    for (int i = 4; i < 8; ++i)
#pragma unroll
      for (int j = 0; j < 4; ++j) acc[i][j] = MFMA16(a0[i], b0[j], acc[i][j]);
    __builtin_amdgcn_s_setprio(0);
    __builtin_amdgcn_s_barrier();

#pragma unroll
    for (int j = 0; j < 4; ++j) {
      const int row = wn * 64 + j * 16 + opr;
      b1[j] = *(const s16x8*)((const char*)Bbc + row * 128 + ((64 + opk2) ^ ((row & 7) << 4)));
    }
    stageA(cur, kt2);
    PH_SYNC();
    __builtin_amdgcn_s_setprio(1);
#pragma unroll
    for (int i = 0; i < 4; ++i)
#pragma unroll
      for (int j = 0; j < 4; ++j) acc[i][j] = MFMA16(a1[i], b1[j], acc[i][j]);
    __builtin_amdgcn_s_setprio(0);
    __builtin_amdgcn_s_barrier();

    stageB(cur, kt2);
    __builtin_amdgcn_s_barrier();
    __builtin_amdgcn_s_setprio(1);
#pragma unroll
    for (int i = 4; i < 8; ++i)
#pragma unroll
      for (int j = 0; j < 4; ++j) acc[i][j] = MFMA16(a1[i], b1[j], acc[i][j]);
    __builtin_amdgcn_s_setprio(0);
    asm volatile("s_waitcnt vmcnt(8)" ::: "memory");
    __builtin_amdgcn_s_barrier();
  }
#undef PH_SYNC

  const int cm = (lane >> 4) << 2;
  const int cn = lane & 15;
#pragma unroll
  for (int i = 0; i < 8; ++i)
#pragma unroll
    for (int j = 0; j < 4; ++j) {
      const int row = tm * 256 + wm * 128 + i * 16 + cm;
      const int col = tn * 256 + wn * 64 + j * 16 + cn;
#pragma unroll
      for (int r = 0; r < 4; ++r) {
        float v = acc[i][j][r];
        if (bf16out) Cb[(size_t)(row + r) * N + col] = f2bf(v);
        else         Cf[(size_t)(row + r) * N + col] = v;
      }
    }
}

// ---------------- bf16 transpose: out[C][R] = in[R][C]^T (in rows strided) ----------------
__global__ __launch_bounds__(256) void transpose_k(const unsigned short* __restrict__ in,
                                                   unsigned short* __restrict__ out,
                                                   int R, int C, int istride) {
  __shared__ unsigned short T[64][68];
  const int tid = threadIdx.x;
  const int nbc = C >> 6;
  const int br = blockIdx.x / nbc;
  const int bc = blockIdx.x % nbc;
  const int r0 = br << 6, c0 = bc << 6;
#pragma unroll
  for (int i = 0; i < 4; ++i) {
    int row = i * 16 + (tid >> 4);
    int col = (tid & 15) << 2;
    *(ushort4*)&T[row][col] = *(const ushort4*)(in + (size_t)(r0 + row) * istride + c0 + col);
  }
  __syncthreads();
#pragma unroll
  for (int i = 0; i < 4; ++i) {
    int row = i * 16 + (tid >> 4);
    int col = (tid & 15) << 2;
    ushort4 v;
    v.x = T[col + 0][row]; v.y = T[col + 1][row];
    v.z = T[col + 2][row]; v.w = T[col + 3][row];
    *(ushort4*)(out + (size_t)(c0 + row) * R + r0 + col) = v;
  }
}

// ---------------- RoPE cos/sin table ----------------
__global__ __launch_bounds__(256) void rope_tab_k(const float* __restrict__ freqs,
                                                  const int* __restrict__ pos,
                                                  float2* __restrict__ tab) {
  int i = blockIdx.x * 256 + threadIdx.x;  // S*64 = 131072
  int s = i >> 6, d = i & 63;
  float ang = freqs[((size_t)(pos[0] + s) << 6) + d];
  float sv, cv;
  sincosf(ang, &sv, &cv);
  tab[i] = make_float2(cv, sv);
}

// ---------------- RoPE apply, in-place on merged qkv buffer ----------------
__global__ __launch_bounds__(256) void rope_k(unsigned short* __restrict__ qkv,
                                              const float2* __restrict__ tab) {
  int idx = blockIdx.x * 256 + threadIdx.x;  // 4096 * 40 * 64
  int d2 = idx & 63;
  int t = idx >> 6;
  int hh = t % (NH + NKV);
  int row = t / (NH + NKV);
  int s = row & (S_LEN - 1);
  float2 cs = tab[(s << 6) + d2];
  unsigned short* p = qkv + (size_t)row * QKVN +
                      (hh < NH ? hh * HD : DMODEL + (hh - NH) * HD) + (d2 << 1);
  unsigned int xy = *(unsigned int*)p;
  float x1 = bf2f((unsigned short)(xy & 0xffffu));
  float x2 = bf2f((unsigned short)(xy >> 16));
  float o1 = x1 * cs.x - x2 * cs.y;
  float o2 = x1 * cs.y + x2 * cs.x;
  *(unsigned int*)p = (unsigned int)f2bf(o1) | ((unsigned int)f2bf(o2) << 16);
}

// ---------------- MFMA flash attention (R8-verified, unchanged) ----------------
__global__ __launch_bounds__(256, 2) void attn_mfma(const unsigned short* __restrict__ qkv,
                                                    const unsigned short* __restrict__ vtb,
                                                    unsigned short* __restrict__ aob) {
  __shared__ alignas(16) unsigned short Ks[64 * 128];    // 16 KB (swizzled)
  __shared__ alignas(16) unsigned short Vts[128 * 64];   // 16 KB (swizzled)
  __shared__ alignas(16) unsigned short Ps[4][32 * 72];  // 18 KB
  const int tid = threadIdx.x;
  const int lane = tid & 63;
  const int w = tid >> 6;
  const int lg = (blockIdx.x & 7) * 128 + (blockIdx.x >> 3);  // grid = 1024
  const int qc = lg & 15;            // 16 q-chunks of 128 rows
  const int hsub = (lg >> 4) & 3;
  const int kvi = (lg >> 6) & 7;
  const int b = lg >> 9;
  const int h = kvi * 4 + hsub;

  const int opr = lane & 15;         // operand row within 16
  const int g = lane >> 4;           // k-subblock 0..3
  const int ak = g * 8;              // operand k offset (shorts)
  const int opk2 = g * 16;           // operand k offset (bytes)
  const int cm = g * 4;              // C/D row base
  const int cn = opr;                // C/D col

  const int qrow0 = b * S_LEN + qc * 128 + w * 32;
  unsigned short* Pw = Ps[w];

  // ---- Q b-frags hoisted once from global ----
  s16x8 qf[2][4];
#pragma unroll
  for (int qb = 0; qb < 2; ++qb)
#pragma unroll
    for (int kk = 0; kk < 4; ++kk)
      qf[qb][kk] = *(const s16x8*)(qkv + (size_t)(qrow0 + qb * 16 + opr) * QKVN +
                                   h * HD + kk * 32 + ak);

  float m_run[2] = {-1e30f, -1e30f};
  float l_run[2] = {0.f, 0.f};
  fx4 acc[8][2] = {};
  const float scale = 0.08838834764831845f;  // 1/sqrt(128)

  for (int t0 = 0; t0 < S_LEN; t0 += 64) {
    __syncthreads();  // prev tile's LDS reads complete
    const size_t krow0 = (size_t)(b * S_LEN + t0);
#pragma unroll
    for (int i = 0; i < 4; ++i) {  // K tile [64][128]
      int d = i * 4096 + tid * 16;
      int row = d >> 8;
      int colb = (d & 255) ^ ((row & 7) << 4);
      GLDS16(qkv + (krow0 + row) * QKVN + DMODEL + kvi * HD + (colb >> 1), (char*)Ks + d);
    }
#pragma unroll
    for (int i = 0; i < 4; ++i) {  // V^T tile [128][64]
      int d = i * 4096 + tid * 16;
      int row = d >> 7;
      int colb = (d & 127) ^ ((row & 7) << 4);
      GLDS16(vtb + (size_t)(kvi * HD + row) * MROWS + (size_t)(b * S_LEN + t0) + (colb >> 1),
             (char*)Vts + d);
    }
    __syncthreads();  // staged data visible (barrier drains vmcnt)

    // ---- S^T[key][q] = MFMA(K-frag, Q-frag) over d=128 ----
    fx4 st[4][2] = {};
#pragma unroll
    for (int kb2 = 0; kb2 < 4; ++kb2) {
      int krow = kb2 * 16 + opr;
      const char* kbase = (const char*)Ks + krow * 256;
      s16x8 kf[4];
#pragma unroll
      for (int kk = 0; kk < 4; ++kk)
        kf[kk] = *(const s16x8*)(kbase + ((kk * 64 + opk2) ^ ((krow & 7) << 4)));
#pragma unroll
      for (int qb = 0; qb < 2; ++qb)
#pragma unroll
        for (int kk = 0; kk < 4; ++kk)
          st[kb2][qb] = MFMA16(kf[kk], qf[qb][kk], st[kb2][qb]);
    }

    // ---- softmax per q-column ----
    float mloc[2], alpha[2], psum[2];
#pragma unroll
    for (int qb = 0; qb < 2; ++qb) {
      float mm = -1e30f;
#pragma unroll
      for (int kb2 = 0; kb2 < 4; ++kb2)
#pragma unroll
        for (int r = 0; r < 4; ++r) mm = fmaxf(mm, st[kb2][qb][r] * scale);
      mm = fmaxf(mm, __shfl_xor(mm, 16));
      mm = fmaxf(mm, __shfl_xor(mm, 32));
      mloc[qb] = mm;
      float mnew = fmaxf(m_run[qb], mm);
      alpha[qb] = __expf(m_run[qb] - mnew);   // first tile: exp(-huge) = 0
      m_run[qb] = mnew;
      psum[qb] = 0.f;
    }
#pragma unroll
    for (int db = 0; db < 8; ++db)
#pragma unroll
      for (int qb = 0; qb < 2; ++qb)
#pragma unroll
        for (int r = 0; r < 4; ++r) acc[db][qb][r] *= alpha[qb];

#pragma unroll
    for (int kb2 = 0; kb2 < 4; ++kb2)
#pragma unroll
      for (int qb = 0; qb < 2; ++qb)
#pragma unroll
        for (int r = 0; r < 4; ++r) {
          float pv = __expf(st[kb2][qb][r] * scale - m_run[qb]);
          psum[qb] += pv;
          Pw[(qb * 16 + cn) * 72 + kb2 * 16 + cm + r] = f2bf(pv);
        }
#pragma unroll
    for (int qb = 0; qb < 2; ++qb) {
      float s = psum[qb];
      s += __shfl_xor(s, 16);
      s += __shfl_xor(s, 32);
      l_run[qb] = l_run[qb] * alpha[qb] + s;
    }

    // ---- P b-frags (wave-private LDS, in-order within wave) ----
    s16x8 pf[2][2];
#pragma unroll
    for (int qb = 0; qb < 2; ++qb)
#pragma unroll
      for (int tb = 0; tb < 2; ++tb)
        pf[qb][tb] = *(const s16x8*)(Pw + (qb * 16 + opr) * 72 + tb * 32 + ak);

    // ---- O^T += MFMA(V^T-frag, P-frag) over t=64 ----
#pragma unroll
    for (int db = 0; db < 8; ++db) {
      int vrow = db * 16 + opr;
      const char* vbase = (const char*)Vts + vrow * 128;
      s16x8 vf[2];
#pragma unroll
      for (int tb = 0; tb < 2; ++tb)
        vf[tb] = *(const s16x8*)(vbase + ((tb * 64 + opk2) ^ ((vrow & 7) << 4)));
#pragma unroll
      for (int qb = 0; qb < 2; ++qb)
#pragma unroll
        for (int tb = 0; tb < 2; ++tb)
          acc[db][qb] = MFMA16(vf[tb], pf[qb][tb], acc[db][qb]);
    }
  }

  // ---- epilogue: normalize per q, pack 4 consecutive d -> 8B ----
  float inv[2] = {1.0f / l_run[0], 1.0f / l_run[1]};
#pragma unroll
  for (int db = 0; db < 8; ++db)
#pragma unroll
    for (int qb = 0; qb < 2; ++qb) {
      ushort4 o;
      o.x = f2bf(acc[db][qb][0] * inv[qb]);
      o.y = f2bf(acc[db][qb][1] * inv[qb]);
      o.z = f2bf(acc[db][qb][2] * inv[qb]);
      o.w = f2bf(acc[db][qb][3] * inv[qb]);
      *(ushort4*)(aob + (size_t)(qrow0 + qb * 16 + cn) * DMODEL + h * HD + db * 16 + cm) = o;
    }
}

// ---------------- launch ----------------
extern "C" void kernel_launch(void* const* d_in, const int* in_sizes, int n_in,
                              void* d_out, int out_size, void* d_ws, size_t ws_size,
                              hipStream_t stream) {
  const float* hs = (const float*)d_in[0];
  const float* fr = (const float*)d_in[1];
  const float* Wq = (const float*)d_in[2];
  const float* Wk = (const float*)d_in[3];
  const float* Wv = (const float*)d_in[4];
  const float* Wo = (const float*)d_in[5];
  const int* pos = (const int*)d_in[6];
  float* out = (float*)d_out;

  // workspace (bf16 elems), total 83,886,080 shorts = 167.8 MB
  unsigned short* w = (unsigned short*)d_ws;
  unsigned short* hsb   = w; w += 16777216;  // [4096,4096] hs bf16 (tab reuses after QKV gemm)
  unsigned short* wqkvb = w; w += 25165824;  // [6144,4096] Wq|Wk|Wv  (aob+vtb reuse after gemm)
  unsigned short* wob   = w; w += 16777216;  // [4096,4096]
  unsigned short* qkvb  = w; w += 25165824;  // [4096,6144] q|k|v per row (rope in-place)
  unsigned short* aob = wqkvb;               // [4096,4096] attn out
  unsigned short* vtb = wqkvb + 16777216;    // [1024,4096] V^T
  float2* tab = (float2*)hsb;                // [2048*64] cos/sin

  if (ws_size < (size_t)83886080 * 2) return;

  cast_all_k<<<57344, 256, 0, stream>>>(hs, Wq, Wk, Wv, Wo, hsb, wqkvb, wob);

  // fused QKV projection: [4096,4096] x [6144,4096]^T -> [4096,6144]
  gemm256<<<384, 512, 0, stream>>>(hsb, wqkvb, nullptr, qkvb, MROWS, QKVN, DMODEL, 1);

  rope_tab_k<<<512, 256, 0, stream>>>(fr, pos, tab);   // hsb dead now
  rope_k<<<40960, 256, 0, stream>>>(qkvb, tab);

  transpose_k<<<1024, 256, 0, stream>>>(qkvb + 5120, vtb, MROWS, 1024, QKVN);  // V -> V^T

  attn_mfma<<<1024, 256, 0, stream>>>(qkvb, vtb, aob);

  // output projection: [4096,4096] x [4096,4096]^T -> f32 out
  gemm256<<<256, 512, 0, stream>>>(aob, wob, out, nullptr, MROWS, DMODEL, DMODEL, 0);
}

// Round 10
// 614.765 us; speedup vs baseline: 1.8449x; 1.0029x over previous
//
#include <hip/hip_runtime.h>

// ---------------- constants ----------------
#define S_LEN 2048
#define NH 32
#define NKV 8
#define HD 128
#define DMODEL 4096
#define MROWS 4096   // B*S
#define QKVN 6144    // 4096 q + 1024 k + 1024 v output cols

typedef short s16x8 __attribute__((ext_vector_type(8)));
typedef float fx4 __attribute__((ext_vector_type(4)));

__device__ __forceinline__ unsigned short f2bf(float f) {
  unsigned int u = __float_as_uint(f);
  u += 0x7fffu + ((u >> 16) & 1u);   // round-to-nearest-even
  return (unsigned short)(u >> 16);
}
__device__ __forceinline__ float bf2f(unsigned short h) {
  return __uint_as_float(((unsigned int)h) << 16);
}

#define GLDS16(gp, lp)                                                        \
  __builtin_amdgcn_global_load_lds(                                           \
      (const __attribute__((address_space(1))) void*)(gp),                    \
      (__attribute__((address_space(3))) void*)(lp), 16, 0, 0)

#define MFMA16(a, b, c) __builtin_amdgcn_mfma_f32_16x16x32_bf16((a), (b), (c), 0, 0, 0)

// ---------------- fused f32 -> bf16 casts (all 5 tensors, one launch) ----------------
__global__ __launch_bounds__(256) void cast_all_k(const float* __restrict__ hs,
                                                  const float* __restrict__ Wq,
                                                  const float* __restrict__ Wk,
                                                  const float* __restrict__ Wv,
                                                  const float* __restrict__ Wo,
                                                  unsigned short* __restrict__ hsb,
                                                  unsigned short* __restrict__ wqkvb,
                                                  unsigned short* __restrict__ wob) {
  int i = blockIdx.x * 256 + threadIdx.x;
  const float* src;
  unsigned short* dst;
  int off;
  if (i < 4194304)       { src = hs; dst = hsb;                off = 0; }
  else if (i < 8388608)  { src = Wq; dst = wqkvb;              off = 4194304; }
  else if (i < 9437184)  { src = Wk; dst = wqkvb + 16777216;   off = 8388608; }
  else if (i < 10485760) { src = Wv; dst = wqkvb + 20971520;   off = 9437184; }
  else                   { src = Wo; dst = wob;                off = 10485760; }
  int j = i - off;
  float4 v = *(const float4*)(src + (size_t)j * 4);
  ushort4 o;
  o.x = f2bf(v.x); o.y = f2bf(v.y); o.z = f2bf(v.z); o.w = f2bf(v.w);
  *(ushort4*)(dst + (size_t)j * 4) = o;
}

// ---------------- 256x256 8-phase bf16 GEMM (R7-verified; O-proj only now) ----------------
__global__ __launch_bounds__(512, 2) void gemm256(const unsigned short* __restrict__ A,
                                                  const unsigned short* __restrict__ Bt,
                                                  float* __restrict__ Cf,
                                                  unsigned short* __restrict__ Cb,
                                                  int M, int N, int K, int bf16out) {
  __shared__ unsigned short Abuf[2][16384];  // [2][256 rows][64 cols]
  __shared__ unsigned short Bbuf[2][16384];
  const int tid = threadIdx.x;
  const int lane = tid & 63;
  const int w = tid >> 6;
  const int wm = w >> 2;   // 0..1
  const int wn = w & 3;    // 0..3

  const int nm = M >> 8;
  const int nn = N >> 8;
  const int rh = nm >> 1;              // rectangle height (tiles)
  const int rw = nn >> 2;              // rectangle width (tiles)
  const int xcd = blockIdx.x & 7;
  const int l = blockIdx.x >> 3;       // per-XCD sequence
  const int tm = (xcd >> 2) * rh + (l % rh);
  const int tn = (xcd & 3) * rw + (l / rh);

  const int opr = lane & 15;
  const int opk2 = (lane >> 4) << 4;   // byte offset {0,16,32,48}
  const int NT = K >> 6;

  const unsigned short* Agbase = A + (size_t)(tm * 256) * K;
  const unsigned short* Bgbase = Bt + (size_t)(tn * 256) * K;
  const int abase = wm * 16384 + wn * 4096;
  const int bbase = (wn >> 1) * 16384 + (wm * 2 + (wn & 1)) * 4096;

  auto stageA = [&](int bsel, int kt) {
#pragma unroll
    for (int r = 0; r < 4; ++r) {
      const int d = abase + r * 1024 + lane * 16;
      const int row = d >> 7;
      const int u = (d & 127) ^ ((row & 7) << 4);
      GLDS16(Agbase + (size_t)row * K + kt * 64 + (u >> 1), (char*)&Abuf[bsel][0] + d);
    }
  };
  auto stageB = [&](int bsel, int kt) {
#pragma unroll
    for (int r = 0; r < 4; ++r) {
      const int d = bbase + r * 1024 + lane * 16;
      const int row = d >> 7;
      const int u = (d & 127) ^ ((row & 7) << 4);
      GLDS16(Bgbase + (size_t)row * K + kt * 64 + (u >> 1), (char*)&Bbuf[bsel][0] + d);
    }
  };

  fx4 acc[8][4] = {};

  stageA(0, 0); stageB(0, 0);
  stageA(1, 1); stageB(1, 1);
  asm volatile("s_waitcnt vmcnt(8)" ::: "memory");
  __builtin_amdgcn_s_barrier();

#define PH_SYNC()                                            \
  do {                                                       \
    __builtin_amdgcn_s_barrier();                            \
    asm volatile("s_waitcnt lgkmcnt(0)" ::: "memory");       \
    __builtin_amdgcn_sched_barrier(0);                       \
  } while (0)

#pragma unroll 1
  for (int t = 0; t < NT; ++t) {
    const int cur = t & 1;
    const unsigned short* Abc = Abuf[cur];
    const unsigned short* Bbc = Bbuf[cur];
    const int kt2 = (t + 2) & (NT - 1);
    s16x8 a0[8], a1[8], b0[4], b1[4];

#pragma unroll
    for (int i = 0; i < 8; ++i) {
      const int row = wm * 128 + i * 16 + opr;
      a0[i] = *(const s16x8*)((const char*)Abc + row * 128 + (opk2 ^ ((row & 7) << 4)));
    }
#pragma unroll
    for (int j = 0; j < 4; ++j) {
      const int row = wn * 64 + j * 16 + opr;
      b0[j] = *(const s16x8*)((const char*)Bbc + row * 128 + (opk2 ^ ((row & 7) << 4)));
    }
    PH_SYNC();
    __builtin_amdgcn_s_setprio(1);
#pragma unroll
    for (int i = 0; i < 4; ++i)
#pragma unroll
      for (int j = 0; j < 4; ++j) acc[i][j] = MFMA16(a0[i], b0[j], acc[i][j]);
    __builtin_amdgcn_s_setprio(0);
    __builtin_amdgcn_s_barrier();

#pragma unroll
    for (int i = 0; i < 8; ++i) {
      const int row = wm * 128 + i * 16 + opr;
      a1[i] = *(const s16x8*)((const char*)Abc + row * 128 + ((64 + opk2) ^ ((row & 7) << 4)));
    }
    PH_SYNC();
    __builtin_amdgcn_s_setprio(1);
#pragma unroll
    for (int i = 4; i < 8; ++i)
#pragma unroll
      for (int j = 0; j < 4; ++j) acc[i][j] = MFMA16(a0[i], b0[j], acc[i][j]);
    __builtin_amdgcn_s_setprio(0);
    __builtin_amdgcn_s_barrier();

#pragma unroll
    for (int j = 0; j < 4; ++j) {
      const int row = wn * 64 + j * 16 + opr;
      b1[j] = *(const s16x8*)((const char*)Bbc + row * 128 + ((64 + opk2) ^ ((row & 7) << 4)));
    }
    stageA(cur, kt2);
    PH_SYNC();
    __builtin_amdgcn_s_setprio(1);
#pragma unroll
    for (int i = 0; i < 4; ++i)
#pragma unroll
      for (int j = 0; j < 4; ++j) acc[i][j] = MFMA16(a1[i], b1[j], acc[i][j]);
    __builtin_amdgcn_s_setprio(0);
    __builtin_amdgcn_s_barrier();

    stageB(cur, kt2);
    __builtin_amdgcn_s_barrier();
    __builtin_amdgcn_s_setprio(1);
#pragma unroll
    for (int i = 4; i < 8; ++i)
#pragma unroll
      for (int j = 0; j < 4; ++j) acc[i][j] = MFMA16(a1[i], b1[j], acc[i][j]);
    __builtin_amdgcn_s_setprio(0);
    asm volatile("s_waitcnt vmcnt(8)" ::: "memory");
    __builtin_amdgcn_s_barrier();
  }
#undef PH_SYNC

  const int cm = (lane >> 4) << 2;
  const int cn = lane & 15;
#pragma unroll
  for (int i = 0; i < 8; ++i)
#pragma unroll
    for (int j = 0; j < 4; ++j) {
      const int row = tm * 256 + wm * 128 + i * 16 + cm;
      const int col = tn * 256 + wn * 64 + j * 16 + cn;
#pragma unroll
      for (int r = 0; r < 4; ++r) {
        float v = acc[i][j][r];
        if (bf16out) Cb[(size_t)(row + r) * N + col] = f2bf(v);
        else         Cf[(size_t)(row + r) * N + col] = v;
      }
    }
}

// ---------------- 128x256 2-phase bf16 GEMM (QKV; grid = (M/128)(N/256) = 768 = 3x256) ----------------
// Same invariants as gemm256: counted vmcnt(6) (6 loads/tile/wave, never 0);
// stage(t+2) into buf[cur] only after the barrier at which every wave has
// passed lgkmcnt(0) for ALL its reads of buf[cur] (all 16 frag reads are in
// ph0). Same swizzle, same per-output summation order as gemm256 (bitwise-
// identical result). 8 waves = 2M(64 rows) x 4N(64 cols); LDS 96 KB.
__global__ __launch_bounds__(512, 2) void gemm128(const unsigned short* __restrict__ A,
                                                  const unsigned short* __restrict__ Bt,
                                                  unsigned short* __restrict__ Cb,
                                                  int M, int N, int K) {
  __shared__ unsigned short Abuf[2][8192];   // [2][128 rows][64 cols]
  __shared__ unsigned short Bbuf[2][16384];  // [2][256 rows][64 cols]
  const int tid = threadIdx.x;
  const int lane = tid & 63;
  const int w = tid >> 6;
  const int wm = w >> 2;   // 0..1 (64-row half)
  const int wn = w & 3;    // 0..3 (64-col quarter)

  const int nm = M >> 7;               // 32
  const int nn = N >> 8;               // 24
  const int rh = nm >> 1;              // 16
  const int rw = nn >> 2;              // 6
  const int xcd = blockIdx.x & 7;
  const int l = blockIdx.x >> 3;       // 0..95
  const int tm = (xcd >> 2) * rh + (l % rh);
  const int tn = (xcd & 3) * rw + (l / rh);

  const int opr = lane & 15;
  const int opk2 = (lane >> 4) << 4;
  const int NT = K >> 6;

  const unsigned short* Agbase = A + (size_t)(tm * 128) * K;
  const unsigned short* Bgbase = Bt + (size_t)(tn * 256) * K;
  const int abase = w * 2048;          // wave's A slice: 16 rows
  const int bbase = w * 4096;          // wave's B slice: 32 rows

  auto stageA = [&](int bsel, int kt) {
#pragma unroll
    for (int r = 0; r < 2; ++r) {
      const int d = abase + r * 1024 + lane * 16;
      const int row = d >> 7;
      const int u = (d & 127) ^ ((row & 7) << 4);
      GLDS16(Agbase + (size_t)row * K + kt * 64 + (u >> 1), (char*)&Abuf[bsel][0] + d);
    }
  };
  auto stageB = [&](int bsel, int kt) {
#pragma unroll
    for (int r = 0; r < 4; ++r) {
      const int d = bbase + r * 1024 + lane * 16;
      const int row = d >> 7;
      const int u = (d & 127) ^ ((row & 7) << 4);
      GLDS16(Bgbase + (size_t)row * K + kt * 64 + (u >> 1), (char*)&Bbuf[bsel][0] + d);
    }
  };

  fx4 acc[4][4] = {};

  stageA(0, 0); stageB(0, 0);
  stageA(1, 1); stageB(1, 1);
  asm volatile("s_waitcnt vmcnt(6)" ::: "memory");
  __builtin_amdgcn_s_barrier();

#pragma unroll 1
  for (int t = 0; t < NT; ++t) {
    const int cur = t & 1;
    const unsigned short* Abc = Abuf[cur];
    const unsigned short* Bbc = Bbuf[cur];
    const int kt2 = (t + 2) & (NT - 1);
    s16x8 a0[4], a1[4], b0[4], b1[4];

    // ---- phase 0: read ALL frags (16 ds_read_b128), MFMA kk0 ----
#pragma unroll
    for (int i = 0; i < 4; ++i) {
      const int row = wm * 64 + i * 16 + opr;
      const char* base = (const char*)Abc + row * 128;
      const int sw = (row & 7) << 4;
      a0[i] = *(const s16x8*)(base + (opk2 ^ sw));
      a1[i] = *(const s16x8*)(base + ((64 + opk2) ^ sw));
    }
#pragma unroll
    for (int j = 0; j < 4; ++j) {
      const int row = wn * 64 + j * 16 + opr;
      const char* base = (const char*)Bbc + row * 128;
      const int sw = (row & 7) << 4;
      b0[j] = *(const s16x8*)(base + (opk2 ^ sw));
      b1[j] = *(const s16x8*)(base + ((64 + opk2) ^ sw));
    }
    __builtin_amdgcn_s_barrier();
    asm volatile("s_waitcnt lgkmcnt(0)" ::: "memory");
    __builtin_amdgcn_sched_barrier(0);
    __builtin_amdgcn_s_setprio(1);
#pragma unroll
    for (int i = 0; i < 4; ++i)
#pragma unroll
      for (int j = 0; j < 4; ++j) acc[i][j] = MFMA16(a0[i], b0[j], acc[i][j]);
    __builtin_amdgcn_s_setprio(0);
    __builtin_amdgcn_s_barrier();  // all waves' buf[cur] reads complete here

    // ---- phase 1: stage tile t+2 (regions now free); MFMA kk1 (reg-only) ----
    stageA(cur, kt2);
    stageB(cur, kt2);
    __builtin_amdgcn_s_setprio(1);
#pragma unroll
    for (int i = 0; i < 4; ++i)
#pragma unroll
      for (int j = 0; j < 4; ++j) acc[i][j] = MFMA16(a1[i], b1[j], acc[i][j]);
    __builtin_amdgcn_s_setprio(0);
    asm volatile("s_waitcnt vmcnt(6)" ::: "memory");  // tile t+1's 6 loads landed
    __builtin_amdgcn_s_barrier();
  }

  // ---- epilogue: C/D layout col=lane&15, row=(lane>>4)*4+reg ----
  const int cm = (lane >> 4) << 2;
  const int cn = lane & 15;
#pragma unroll
  for (int i = 0; i < 4; ++i)
#pragma unroll
    for (int j = 0; j < 4; ++j) {
      const int row = tm * 128 + wm * 64 + i * 16 + cm;
      const int col = tn * 256 + wn * 64 + j * 16 + cn;
#pragma unroll
      for (int r = 0; r < 4; ++r)
        Cb[(size_t)(row + r) * N + col] = f2bf(acc[i][j][r]);
    }
}

// ---------------- bf16 transpose: out[C][R] = in[R][C]^T (in rows strided) ----------------
__global__ __launch_bounds__(256) void transpose_k(const unsigned short* __restrict__ in,
                                                   unsigned short* __restrict__ out,
                                                   int R, int C, int istride) {
  __shared__ unsigned short T[64][68];
  const int tid = threadIdx.x;
  const int nbc = C >> 6;
  const int br = blockIdx.x / nbc;
  const int bc = blockIdx.x % nbc;
  const int r0 = br << 6, c0 = bc << 6;
#pragma unroll
  for (int i = 0; i < 4; ++i) {
    int row = i * 16 + (tid >> 4);
    int col = (tid & 15) << 2;
    *(ushort4*)&T[row][col] = *(const ushort4*)(in + (size_t)(r0 + row) * istride + c0 + col);
  }
  __syncthreads();
#pragma unroll
  for (int i = 0; i < 4; ++i) {
    int row = i * 16 + (tid >> 4);
    int col = (tid & 15) << 2;
    ushort4 v;
    v.x = T[col + 0][row]; v.y = T[col + 1][row];
    v.z = T[col + 2][row]; v.w = T[col + 3][row];
    *(ushort4*)(out + (size_t)(c0 + row) * R + r0 + col) = v;
  }
}

// ---------------- RoPE cos/sin table ----------------
__global__ __launch_bounds__(256) void rope_tab_k(const float* __restrict__ freqs,
                                                  const int* __restrict__ pos,
                                                  float2* __restrict__ tab) {
  int i = blockIdx.x * 256 + threadIdx.x;  // S*64 = 131072
  int s = i >> 6, d = i & 63;
  float ang = freqs[((size_t)(pos[0] + s) << 6) + d];
  float sv, cv;
  sincosf(ang, &sv, &cv);
  tab[i] = make_float2(cv, sv);
}

// ---------------- RoPE apply, in-place on merged qkv buffer ----------------
__global__ __launch_bounds__(256) void rope_k(unsigned short* __restrict__ qkv,
                                              const float2* __restrict__ tab) {
  int idx = blockIdx.x * 256 + threadIdx.x;  // 4096 * 40 * 64
  int d2 = idx & 63;
  int t = idx >> 6;
  int hh = t % (NH + NKV);
  int row = t / (NH + NKV);
  int s = row & (S_LEN - 1);
  float2 cs = tab[(s << 6) + d2];
  unsigned short* p = qkv + (size_t)row * QKVN +
                      (hh < NH ? hh * HD : DMODEL + (hh - NH) * HD) + (d2 << 1);
  unsigned int xy = *(unsigned int*)p;
  float x1 = bf2f((unsigned short)(xy & 0xffffu));
  float x2 = bf2f((unsigned short)(xy >> 16));
  float o1 = x1 * cs.x - x2 * cs.y;
  float o2 = x1 * cs.y + x2 * cs.x;
  *(unsigned int*)p = (unsigned int)f2bf(o1) | ((unsigned int)f2bf(o2) << 16);
}

// ---------------- MFMA flash attention (R8-verified, unchanged) ----------------
__global__ __launch_bounds__(256, 2) void attn_mfma(const unsigned short* __restrict__ qkv,
                                                    const unsigned short* __restrict__ vtb,
                                                    unsigned short* __restrict__ aob) {
  __shared__ alignas(16) unsigned short Ks[64 * 128];    // 16 KB (swizzled)
  __shared__ alignas(16) unsigned short Vts[128 * 64];   // 16 KB (swizzled)
  __shared__ alignas(16) unsigned short Ps[4][32 * 72];  // 18 KB
  const int tid = threadIdx.x;
  const int lane = tid & 63;
  const int w = tid >> 6;
  const int lg = (blockIdx.x & 7) * 128 + (blockIdx.x >> 3);  // grid = 1024
  const int qc = lg & 15;            // 16 q-chunks of 128 rows
  const int hsub = (lg >> 4) & 3;
  const int kvi = (lg >> 6) & 7;
  const int b = lg >> 9;
  const int h = kvi * 4 + hsub;

  const int opr = lane & 15;         // operand row within 16
  const int g = lane >> 4;           // k-subblock 0..3
  const int ak = g * 8;              // operand k offset (shorts)
  const int opk2 = g * 16;           // operand k offset (bytes)
  const int cm = g * 4;              // C/D row base
  const int cn = opr;                // C/D col

  const int qrow0 = b * S_LEN + qc * 128 + w * 32;
  unsigned short* Pw = Ps[w];

  // ---- Q b-frags hoisted once from global ----
  s16x8 qf[2][4];
#pragma unroll
  for (int qb = 0; qb < 2; ++qb)
#pragma unroll
    for (int kk = 0; kk < 4; ++kk)
      qf[qb][kk] = *(const s16x8*)(qkv + (size_t)(qrow0 + qb * 16 + opr) * QKVN +
                                   h * HD + kk * 32 + ak);

  float m_run[2] = {-1e30f, -1e30f};
  float l_run[2] = {0.f, 0.f};
  fx4 acc[8][2] = {};
  const float scale = 0.08838834764831845f;  // 1/sqrt(128)

  for (int t0 = 0; t0 < S_LEN; t0 += 64) {
    __syncthreads();  // prev tile's LDS reads complete
    const size_t krow0 = (size_t)(b * S_LEN + t0);
#pragma unroll
    for (int i = 0; i < 4; ++i) {  // K tile [64][128]
      int d = i * 4096 + tid * 16;
      int row = d >> 8;
      int colb = (d & 255) ^ ((row & 7) << 4);
      GLDS16(qkv + (krow0 + row) * QKVN + DMODEL + kvi * HD + (colb >> 1), (char*)Ks + d);
    }
#pragma unroll
    for (int i = 0; i < 4; ++i) {  // V^T tile [128][64]
      int d = i * 4096 + tid * 16;
      int row = d >> 7;
      int colb = (d & 127) ^ ((row & 7) << 4);
      GLDS16(vtb + (size_t)(kvi * HD + row) * MROWS + (size_t)(b * S_LEN + t0) + (colb >> 1),
             (char*)Vts + d);
    }
    __syncthreads();  // staged data visible (barrier drains vmcnt)

    // ---- S^T[key][q] = MFMA(K-frag, Q-frag) over d=128 ----
    fx4 st[4][2] = {};
#pragma unroll
    for (int kb2 = 0; kb2 < 4; ++kb2) {
      int krow = kb2 * 16 + opr;
      const char* kbase = (const char*)Ks + krow * 256;
      s16x8 kf[4];
#pragma unroll
      for (int kk = 0; kk < 4; ++kk)
        kf[kk] = *(const s16x8*)(kbase + ((kk * 64 + opk2) ^ ((krow & 7) << 4)));
#pragma unroll
      for (int qb = 0; qb < 2; ++qb)
#pragma unroll
        for (int kk = 0; kk < 4; ++kk)
          st[kb2][qb] = MFMA16(kf[kk], qf[qb][kk], st[kb2][qb]);
    }

    // ---- softmax per q-column ----
    float mloc[2], alpha[2], psum[2];
#pragma unroll
    for (int qb = 0; qb < 2; ++qb) {
      float mm = -1e30f;
#pragma unroll
      for (int kb2 = 0; kb2 < 4; ++kb2)
#pragma unroll
        for (int r = 0; r < 4; ++r) mm = fmaxf(mm, st[kb2][qb][r] * scale);
      mm = fmaxf(mm, __shfl_xor(mm, 16));
      mm = fmaxf(mm, __shfl_xor(mm, 32));
      mloc[qb] = mm;
      float mnew = fmaxf(m_run[qb], mm);
      alpha[qb] = __expf(m_run[qb] - mnew);   // first tile: exp(-huge) = 0
      m_run[qb] = mnew;
      psum[qb] = 0.f;
    }
#pragma unroll
    for (int db = 0; db < 8; ++db)
#pragma unroll
      for (int qb = 0; qb < 2; ++qb)
#pragma unroll
        for (int r = 0; r < 4; ++r) acc[db][qb][r] *= alpha[qb];

#pragma unroll
    for (int kb2 = 0; kb2 < 4; ++kb2)
#pragma unroll
      for (int qb = 0; qb < 2; ++qb)
#pragma unroll
        for (int r = 0; r < 4; ++r) {
          float pv = __expf(st[kb2][qb][r] * scale - m_run[qb]);
          psum[qb] += pv;
          Pw[(qb * 16 + cn) * 72 + kb2 * 16 + cm + r] = f2bf(pv);
        }
#pragma unroll
    for (int qb = 0; qb < 2; ++qb) {
      float s = psum[qb];
      s += __shfl_xor(s, 16);
      s += __shfl_xor(s, 32);
      l_run[qb] = l_run[qb] * alpha[qb] + s;
    }

    // ---- P b-frags (wave-private LDS, in-order within wave) ----
    s16x8 pf[2][2];
#pragma unroll
    for (int qb = 0; qb < 2; ++qb)
#pragma unroll
      for (int tb = 0; tb < 2; ++tb)
        pf[qb][tb] = *(const s16x8*)(Pw + (qb * 16 + opr) * 72 + tb * 32 + ak);

    // ---- O^T += MFMA(V^T-frag, P-frag) over t=64 ----
#pragma unroll
    for (int db = 0; db < 8; ++db) {
      int vrow = db * 16 + opr;
      const char* vbase = (const char*)Vts + vrow * 128;
      s16x8 vf[2];
#pragma unroll
      for (int tb = 0; tb < 2; ++tb)
        vf[tb] = *(const s16x8*)(vbase + ((tb * 64 + opk2) ^ ((vrow & 7) << 4)));
#pragma unroll
      for (int qb = 0; qb < 2; ++qb)
#pragma unroll
        for (int tb = 0; tb < 2; ++tb)
          acc[db][qb] = MFMA16(vf[tb], pf[qb][tb], acc[db][qb]);
    }
  }

  // ---- epilogue: normalize per q, pack 4 consecutive d -> 8B ----
  float inv[2] = {1.0f / l_run[0], 1.0f / l_run[1]};
#pragma unroll
  for (int db = 0; db < 8; ++db)
#pragma unroll
    for (int qb = 0; qb < 2; ++qb) {
      ushort4 o;
      o.x = f2bf(acc[db][qb][0] * inv[qb]);
      o.y = f2bf(acc[db][qb][1] * inv[qb]);
      o.z = f2bf(acc[db][qb][2] * inv[qb]);
      o.w = f2bf(acc[db][qb][3] * inv[qb]);
      *(ushort4*)(aob + (size_t)(qrow0 + qb * 16 + cn) * DMODEL + h * HD + db * 16 + cm) = o;
    }
}

// ---------------- launch ----------------
extern "C" void kernel_launch(void* const* d_in, const int* in_sizes, int n_in,
                              void* d_out, int out_size, void* d_ws, size_t ws_size,
                              hipStream_t stream) {
  const float* hs = (const float*)d_in[0];
  const float* fr = (const float*)d_in[1];
  const float* Wq = (const float*)d_in[2];
  const float* Wk = (const float*)d_in[3];
  const float* Wv = (const float*)d_in[4];
  const float* Wo = (const float*)d_in[5];
  const int* pos = (const int*)d_in[6];
  float* out = (float*)d_out;

  // workspace (bf16 elems), total 83,886,080 shorts = 167.8 MB
  unsigned short* w = (unsigned short*)d_ws;
  unsigned short* hsb   = w; w += 16777216;  // [4096,4096] hs bf16 (tab reuses after QKV gemm)
  unsigned short* wqkvb = w; w += 25165824;  // [6144,4096] Wq|Wk|Wv  (aob+vtb reuse after gemm)
  unsigned short* wob   = w; w += 16777216;  // [4096,4096]
  unsigned short* qkvb  = w; w += 25165824;  // [4096,6144] q|k|v per row (rope in-place)
  unsigned short* aob = wqkvb;               // [4096,4096] attn out
  unsigned short* vtb = wqkvb + 16777216;    // [1024,4096] V^T
  float2* tab = (float2*)hsb;                // [2048*64] cos/sin

  if (ws_size < (size_t)83886080 * 2) return;

  cast_all_k<<<57344, 256, 0, stream>>>(hs, Wq, Wk, Wv, Wo, hsb, wqkvb, wob);

  // fused QKV projection: [4096,4096] x [6144,4096]^T -> [4096,6144]
  gemm128<<<768, 512, 0, stream>>>(hsb, wqkvb, qkvb, MROWS, QKVN, DMODEL);

  rope_tab_k<<<512, 256, 0, stream>>>(fr, pos, tab);   // hsb dead now
  rope_k<<<40960, 256, 0, stream>>>(qkvb, tab);

  transpose_k<<<1024, 256, 0, stream>>>(qkvb + 5120, vtb, MROWS, 1024, QKVN);  // V -> V^T

  attn_mfma<<<1024, 256, 0, stream>>>(qkvb, vtb, aob);

  // output projection: [4096,4096] x [4096,4096]^T -> f32 out
  gemm256<<<256, 512, 0, stream>>>(aob, wob, out, nullptr, MROWS, DMODEL, DMODEL, 0);
}

// Round 11
// 595.490 us; speedup vs baseline: 1.9046x; 1.0324x over previous
//
#include <hip/hip_runtime.h>

// ---------------- constants ----------------
#define S_LEN 2048
#define NH 32
#define NKV 8
#define HD 128
#define DMODEL 4096
#define MROWS 4096   // B*S
#define QKVN 6144    // 4096 q + 1024 k + 1024 v output cols

typedef short s16x8 __attribute__((ext_vector_type(8)));
typedef float fx4 __attribute__((ext_vector_type(4)));

__device__ __forceinline__ unsigned short f2bf(float f) {
  unsigned int u = __float_as_uint(f);
  u += 0x7fffu + ((u >> 16) & 1u);   // round-to-nearest-even
  return (unsigned short)(u >> 16);
}
__device__ __forceinline__ float bf2f(unsigned short h) {
  return __uint_as_float(((unsigned int)h) << 16);
}

#define GLDS16(gp, lp)                                                        \
  __builtin_amdgcn_global_load_lds(                                           \
      (const __attribute__((address_space(1))) void*)(gp),                    \
      (__attribute__((address_space(3))) void*)(lp), 16, 0, 0)

#define MFMA16(a, b, c) __builtin_amdgcn_mfma_f32_16x16x32_bf16((a), (b), (c), 0, 0, 0)

// ---------------- fused f32 -> bf16 casts (all 5 tensors, one launch) ----------------
__global__ __launch_bounds__(256) void cast_all_k(const float* __restrict__ hs,
                                                  const float* __restrict__ Wq,
                                                  const float* __restrict__ Wk,
                                                  const float* __restrict__ Wv,
                                                  const float* __restrict__ Wo,
                                                  unsigned short* __restrict__ hsb,
                                                  unsigned short* __restrict__ wqkvb,
                                                  unsigned short* __restrict__ wob) {
  int i = blockIdx.x * 256 + threadIdx.x;
  const float* src;
  unsigned short* dst;
  int off;
  if (i < 4194304)       { src = hs; dst = hsb;                off = 0; }
  else if (i < 8388608)  { src = Wq; dst = wqkvb;              off = 4194304; }
  else if (i < 9437184)  { src = Wk; dst = wqkvb + 16777216;   off = 8388608; }
  else if (i < 10485760) { src = Wv; dst = wqkvb + 20971520;   off = 9437184; }
  else                   { src = Wo; dst = wob;                off = 10485760; }
  int j = i - off;
  float4 v = *(const float4*)(src + (size_t)j * 4);
  ushort4 o;
  o.x = f2bf(v.x); o.y = f2bf(v.y); o.z = f2bf(v.z); o.w = f2bf(v.w);
  *(ushort4*)(dst + (size_t)j * 4) = o;
}

// ---------------- 256x256 8-phase bf16 GEMM (R7-verified; O-proj, grid=256 clean) ----------------
__global__ __launch_bounds__(512, 2) void gemm256(const unsigned short* __restrict__ A,
                                                  const unsigned short* __restrict__ Bt,
                                                  float* __restrict__ Cf,
                                                  unsigned short* __restrict__ Cb,
                                                  int M, int N, int K, int bf16out) {
  __shared__ unsigned short Abuf[2][16384];  // [2][256 rows][64 cols]
  __shared__ unsigned short Bbuf[2][16384];
  const int tid = threadIdx.x;
  const int lane = tid & 63;
  const int w = tid >> 6;
  const int wm = w >> 2;   // 0..1
  const int wn = w & 3;    // 0..3

  const int nm = M >> 8;
  const int nn = N >> 8;
  const int rh = nm >> 1;              // rectangle height (tiles)
  const int rw = nn >> 2;              // rectangle width (tiles)
  const int xcd = blockIdx.x & 7;
  const int l = blockIdx.x >> 3;       // per-XCD sequence
  const int tm = (xcd >> 2) * rh + (l % rh);
  const int tn = (xcd & 3) * rw + (l / rh);

  const int opr = lane & 15;
  const int opk2 = (lane >> 4) << 4;   // byte offset {0,16,32,48}
  const int NT = K >> 6;

  const unsigned short* Agbase = A + (size_t)(tm * 256) * K;
  const unsigned short* Bgbase = Bt + (size_t)(tn * 256) * K;
  const int abase = wm * 16384 + wn * 4096;
  const int bbase = (wn >> 1) * 16384 + (wm * 2 + (wn & 1)) * 4096;

  auto stageA = [&](int bsel, int kt) {
#pragma unroll
    for (int r = 0; r < 4; ++r) {
      const int d = abase + r * 1024 + lane * 16;
      const int row = d >> 7;
      const int u = (d & 127) ^ ((row & 7) << 4);
      GLDS16(Agbase + (size_t)row * K + kt * 64 + (u >> 1), (char*)&Abuf[bsel][0] + d);
    }
  };
  auto stageB = [&](int bsel, int kt) {
#pragma unroll
    for (int r = 0; r < 4; ++r) {
      const int d = bbase + r * 1024 + lane * 16;
      const int row = d >> 7;
      const int u = (d & 127) ^ ((row & 7) << 4);
      GLDS16(Bgbase + (size_t)row * K + kt * 64 + (u >> 1), (char*)&Bbuf[bsel][0] + d);
    }
  };

  fx4 acc[8][4] = {};

  stageA(0, 0); stageB(0, 0);
  stageA(1, 1); stageB(1, 1);
  asm volatile("s_waitcnt vmcnt(8)" ::: "memory");
  __builtin_amdgcn_s_barrier();

#define PH_SYNC()                                            \
  do {                                                       \
    __builtin_amdgcn_s_barrier();                            \
    asm volatile("s_waitcnt lgkmcnt(0)" ::: "memory");       \
    __builtin_amdgcn_sched_barrier(0);                       \
  } while (0)

#pragma unroll 1
  for (int t = 0; t < NT; ++t) {
    const int cur = t & 1;
    const unsigned short* Abc = Abuf[cur];
    const unsigned short* Bbc = Bbuf[cur];
    const int kt2 = (t + 2) & (NT - 1);
    s16x8 a0[8], a1[8], b0[4], b1[4];

#pragma unroll
    for (int i = 0; i < 8; ++i) {
      const int row = wm * 128 + i * 16 + opr;
      a0[i] = *(const s16x8*)((const char*)Abc + row * 128 + (opk2 ^ ((row & 7) << 4)));
    }
#pragma unroll
    for (int j = 0; j < 4; ++j) {
      const int row = wn * 64 + j * 16 + opr;
      b0[j] = *(const s16x8*)((const char*)Bbc + row * 128 + (opk2 ^ ((row & 7) << 4)));
    }
    PH_SYNC();
    __builtin_amdgcn_s_setprio(1);
#pragma unroll
    for (int i = 0; i < 4; ++i)
#pragma unroll
      for (int j = 0; j < 4; ++j) acc[i][j] = MFMA16(a0[i], b0[j], acc[i][j]);
    __builtin_amdgcn_s_setprio(0);
    __builtin_amdgcn_s_barrier();

#pragma unroll
    for (int i = 0; i < 8; ++i) {
      const int row = wm * 128 + i * 16 + opr;
      a1[i] = *(const s16x8*)((const char*)Abc + row * 128 + ((64 + opk2) ^ ((row & 7) << 4)));
    }
    PH_SYNC();
    __builtin_amdgcn_s_setprio(1);
#pragma unroll
    for (int i = 4; i < 8; ++i)
#pragma unroll
      for (int j = 0; j < 4; ++j) acc[i][j] = MFMA16(a0[i], b0[j], acc[i][j]);
    __builtin_amdgcn_s_setprio(0);
    __builtin_amdgcn_s_barrier();

#pragma unroll
    for (int j = 0; j < 4; ++j) {
      const int row = wn * 64 + j * 16 + opr;
      b1[j] = *(const s16x8*)((const char*)Bbc + row * 128 + ((64 + opk2) ^ ((row & 7) << 4)));
    }
    stageA(cur, kt2);
    PH_SYNC();
    __builtin_amdgcn_s_setprio(1);
#pragma unroll
    for (int i = 0; i < 4; ++i)
#pragma unroll
      for (int j = 0; j < 4; ++j) acc[i][j] = MFMA16(a1[i], b1[j], acc[i][j]);
    __builtin_amdgcn_s_setprio(0);
    __builtin_amdgcn_s_barrier();

    stageB(cur, kt2);
    __builtin_amdgcn_s_barrier();
    __builtin_amdgcn_s_setprio(1);
#pragma unroll
    for (int i = 4; i < 8; ++i)
#pragma unroll
      for (int j = 0; j < 4; ++j) acc[i][j] = MFMA16(a1[i], b1[j], acc[i][j]);
    __builtin_amdgcn_s_setprio(0);
    asm volatile("s_waitcnt vmcnt(8)" ::: "memory");
    __builtin_amdgcn_s_barrier();
  }
#undef PH_SYNC

  const int cm = (lane >> 4) << 2;
  const int cn = lane & 15;
#pragma unroll
  for (int i = 0; i < 8; ++i)
#pragma unroll
    for (int j = 0; j < 4; ++j) {
      const int row = tm * 256 + wm * 128 + i * 16 + cm;
      const int col = tn * 256 + wn * 64 + j * 16 + cn;
#pragma unroll
      for (int r = 0; r < 4; ++r) {
        float v = acc[i][j][r];
        if (bf16out) Cb[(size_t)(row + r) * N + col] = f2bf(v);
        else         Cf[(size_t)(row + r) * N + col] = v;
      }
    }
}

// ---------------- 256x192 8-phase bf16 GEMM (QKV; grid = 16x32 = 512 = 2x256 clean) ----------------
// Parameter variant of the R7-verified gemm256 template (same phase/sync
// structure, same invariants): BN 256->192, wave n-frags 4->3, stageB loads
// 4->3 (wave stages rows [24w,24w+24)), counted vmcnt(7) = tile's 7 loads/wave.
// A-region reads complete at P1-end barrier -> stageA@P2 safe; B-reads complete
// at P2-end barrier -> stageB@P3 safe (identical proof to gemm256).
__global__ __launch_bounds__(512, 2) void gemm192(const unsigned short* __restrict__ A,
                                                  const unsigned short* __restrict__ Bt,
                                                  unsigned short* __restrict__ Cb,
                                                  int M, int N, int K) {
  __shared__ unsigned short Abuf[2][16384];  // [2][256 rows][64 cols]
  __shared__ unsigned short Bbuf[2][12288];  // [2][192 rows][64 cols]
  const int tid = threadIdx.x;
  const int lane = tid & 63;
  const int w = tid >> 6;
  const int wm = w >> 2;   // 0..1
  const int wn = w & 3;    // 0..3

  const int nm = M >> 8;               // 16
  const int nn = N / 192;              // 32
  const int rh = nm >> 1;              // 8
  const int rw = nn >> 2;              // 8
  const int xcd = blockIdx.x & 7;
  const int l = blockIdx.x >> 3;       // 0..63
  const int tm = (xcd >> 2) * rh + (l % rh);
  const int tn = (xcd & 3) * rw + (l / rh);

  const int opr = lane & 15;
  const int opk2 = (lane >> 4) << 4;
  const int NT = K >> 6;

  const unsigned short* Agbase = A + (size_t)(tm * 256) * K;
  const unsigned short* Bgbase = Bt + (size_t)(tn * 192) * K;
  const int abase = wm * 16384 + wn * 4096;  // wave stages 32 A-rows
  const int bbase = w * 3072;                // wave stages 24 B-rows

  auto stageA = [&](int bsel, int kt) {
#pragma unroll
    for (int r = 0; r < 4; ++r) {
      const int d = abase + r * 1024 + lane * 16;
      const int row = d >> 7;
      const int u = (d & 127) ^ ((row & 7) << 4);
      GLDS16(Agbase + (size_t)row * K + kt * 64 + (u >> 1), (char*)&Abuf[bsel][0] + d);
    }
  };
  auto stageB = [&](int bsel, int kt) {
#pragma unroll
    for (int r = 0; r < 3; ++r) {
      const int d = bbase + r * 1024 + lane * 16;
      const int row = d >> 7;
      const int u = (d & 127) ^ ((row & 7) << 4);
      GLDS16(Bgbase + (size_t)row * K + kt * 64 + (u >> 1), (char*)&Bbuf[bsel][0] + d);
    }
  };

  fx4 acc[8][3] = {};

  stageA(0, 0); stageB(0, 0);
  stageA(1, 1); stageB(1, 1);
  asm volatile("s_waitcnt vmcnt(7)" ::: "memory");  // tile0's 7 loads landed
  __builtin_amdgcn_s_barrier();

#define PH_SYNC()                                            \
  do {                                                       \
    __builtin_amdgcn_s_barrier();                            \
    asm volatile("s_waitcnt lgkmcnt(0)" ::: "memory");       \
    __builtin_amdgcn_sched_barrier(0);                       \
  } while (0)

#pragma unroll 1
  for (int t = 0; t < NT; ++t) {
    const int cur = t & 1;
    const unsigned short* Abc = Abuf[cur];
    const unsigned short* Bbc = Bbuf[cur];
    const int kt2 = (t + 2) & (NT - 1);
    s16x8 a0[8], a1[8], b0[3], b1[3];

#pragma unroll
    for (int i = 0; i < 8; ++i) {
      const int row = wm * 128 + i * 16 + opr;
      a0[i] = *(const s16x8*)((const char*)Abc + row * 128 + (opk2 ^ ((row & 7) << 4)));
    }
#pragma unroll
    for (int j = 0; j < 3; ++j) {
      const int row = wn * 48 + j * 16 + opr;
      b0[j] = *(const s16x8*)((const char*)Bbc + row * 128 + (opk2 ^ ((row & 7) << 4)));
    }
    PH_SYNC();
    __builtin_amdgcn_s_setprio(1);
#pragma unroll
    for (int i = 0; i < 4; ++i)
#pragma unroll
      for (int j = 0; j < 3; ++j) acc[i][j] = MFMA16(a0[i], b0[j], acc[i][j]);
    __builtin_amdgcn_s_setprio(0);
    __builtin_amdgcn_s_barrier();

#pragma unroll
    for (int i = 0; i < 8; ++i) {
      const int row = wm * 128 + i * 16 + opr;
      a1[i] = *(const s16x8*)((const char*)Abc + row * 128 + ((64 + opk2) ^ ((row & 7) << 4)));
    }
    PH_SYNC();
    __builtin_amdgcn_s_setprio(1);
#pragma unroll
    for (int i = 4; i < 8; ++i)
#pragma unroll
      for (int j = 0; j < 3; ++j) acc[i][j] = MFMA16(a0[i], b0[j], acc[i][j]);
    __builtin_amdgcn_s_setprio(0);
    __builtin_amdgcn_s_barrier();

#pragma unroll
    for (int j = 0; j < 3; ++j) {
      const int row = wn * 48 + j * 16 + opr;
      b1[j] = *(const s16x8*)((const char*)Bbc + row * 128 + ((64 + opk2) ^ ((row & 7) << 4)));
    }
    stageA(cur, kt2);
    PH_SYNC();
    __builtin_amdgcn_s_setprio(1);
#pragma unroll
    for (int i = 0; i < 4; ++i)
#pragma unroll
      for (int j = 0; j < 3; ++j) acc[i][j] = MFMA16(a1[i], b1[j], acc[i][j]);
    __builtin_amdgcn_s_setprio(0);
    __builtin_amdgcn_s_barrier();

    stageB(cur, kt2);
    __builtin_amdgcn_s_barrier();
    __builtin_amdgcn_s_setprio(1);
#pragma unroll
    for (int i = 4; i < 8; ++i)
#pragma unroll
      for (int j = 0; j < 3; ++j) acc[i][j] = MFMA16(a1[i], b1[j], acc[i][j]);
    __builtin_amdgcn_s_setprio(0);
    asm volatile("s_waitcnt vmcnt(7)" ::: "memory");  // tile t+1's 7 loads landed
    __builtin_amdgcn_s_barrier();
  }
#undef PH_SYNC

  const int cm = (lane >> 4) << 2;
  const int cn = lane & 15;
#pragma unroll
  for (int i = 0; i < 8; ++i)
#pragma unroll
    for (int j = 0; j < 3; ++j) {
      const int row = tm * 256 + wm * 128 + i * 16 + cm;
      const int col = tn * 192 + wn * 48 + j * 16 + cn;
#pragma unroll
      for (int r = 0; r < 4; ++r)
        Cb[(size_t)(row + r) * N + col] = f2bf(acc[i][j][r]);
    }
}

// ---------------- bf16 transpose: out[C][R] = in[R][C]^T (in rows strided) ----------------
__global__ __launch_bounds__(256) void transpose_k(const unsigned short* __restrict__ in,
                                                   unsigned short* __restrict__ out,
                                                   int R, int C, int istride) {
  __shared__ unsigned short T[64][68];
  const int tid = threadIdx.x;
  const int nbc = C >> 6;
  const int br = blockIdx.x / nbc;
  const int bc = blockIdx.x % nbc;
  const int r0 = br << 6, c0 = bc << 6;
#pragma unroll
  for (int i = 0; i < 4; ++i) {
    int row = i * 16 + (tid >> 4);
    int col = (tid & 15) << 2;
    *(ushort4*)&T[row][col] = *(const ushort4*)(in + (size_t)(r0 + row) * istride + c0 + col);
  }
  __syncthreads();
#pragma unroll
  for (int i = 0; i < 4; ++i) {
    int row = i * 16 + (tid >> 4);
    int col = (tid & 15) << 2;
    ushort4 v;
    v.x = T[col + 0][row]; v.y = T[col + 1][row];
    v.z = T[col + 2][row]; v.w = T[col + 3][row];
    *(ushort4*)(out + (size_t)(c0 + row) * R + r0 + col) = v;
  }
}

// ---------------- RoPE cos/sin table ----------------
__global__ __launch_bounds__(256) void rope_tab_k(const float* __restrict__ freqs,
                                                  const int* __restrict__ pos,
                                                  float2* __restrict__ tab) {
  int i = blockIdx.x * 256 + threadIdx.x;  // S*64 = 131072
  int s = i >> 6, d = i & 63;
  float ang = freqs[((size_t)(pos[0] + s) << 6) + d];
  float sv, cv;
  sincosf(ang, &sv, &cv);
  tab[i] = make_float2(cv, sv);
}

// ---------------- RoPE apply, in-place on merged qkv buffer ----------------
__global__ __launch_bounds__(256) void rope_k(unsigned short* __restrict__ qkv,
                                              const float2* __restrict__ tab) {
  int idx = blockIdx.x * 256 + threadIdx.x;  // 4096 * 40 * 64
  int d2 = idx & 63;
  int t = idx >> 6;
  int hh = t % (NH + NKV);
  int row = t / (NH + NKV);
  int s = row & (S_LEN - 1);
  float2 cs = tab[(s << 6) + d2];
  unsigned short* p = qkv + (size_t)row * QKVN +
                      (hh < NH ? hh * HD : DMODEL + (hh - NH) * HD) + (d2 << 1);
  unsigned int xy = *(unsigned int*)p;
  float x1 = bf2f((unsigned short)(xy & 0xffffu));
  float x2 = bf2f((unsigned short)(xy >> 16));
  float o1 = x1 * cs.x - x2 * cs.y;
  float o2 = x1 * cs.y + x2 * cs.x;
  *(unsigned int*)p = (unsigned int)f2bf(o1) | ((unsigned int)f2bf(o2) << 16);
}

// ---------------- MFMA flash attention (R8-verified, unchanged) ----------------
__global__ __launch_bounds__(256, 2) void attn_mfma(const unsigned short* __restrict__ qkv,
                                                    const unsigned short* __restrict__ vtb,
                                                    unsigned short* __restrict__ aob) {
  __shared__ alignas(16) unsigned short Ks[64 * 128];    // 16 KB (swizzled)
  __shared__ alignas(16) unsigned short Vts[128 * 64];   // 16 KB (swizzled)
  __shared__ alignas(16) unsigned short Ps[4][32 * 72];  // 18 KB
  const int tid = threadIdx.x;
  const int lane = tid & 63;
  const int w = tid >> 6;
  const int lg = (blockIdx.x & 7) * 128 + (blockIdx.x >> 3);  // grid = 1024
  const int qc = lg & 15;            // 16 q-chunks of 128 rows
  const int hsub = (lg >> 4) & 3;
  const int kvi = (lg >> 6) & 7;
  const int b = lg >> 9;
  const int h = kvi * 4 + hsub;

  const int opr = lane & 15;         // operand row within 16
  const int g = lane >> 4;           // k-subblock 0..3
  const int ak = g * 8;              // operand k offset (shorts)
  const int opk2 = g * 16;           // operand k offset (bytes)
  const int cm = g * 4;              // C/D row base
  const int cn = opr;                // C/D col

  const int qrow0 = b * S_LEN + qc * 128 + w * 32;
  unsigned short* Pw = Ps[w];

  // ---- Q b-frags hoisted once from global ----
  s16x8 qf[2][4];
#pragma unroll
  for (int qb = 0; qb < 2; ++qb)
#pragma unroll
    for (int kk = 0; kk < 4; ++kk)
      qf[qb][kk] = *(const s16x8*)(qkv + (size_t)(qrow0 + qb * 16 + opr) * QKVN +
                                   h * HD + kk * 32 + ak);

  float m_run[2] = {-1e30f, -1e30f};
  float l_run[2] = {0.f, 0.f};
  fx4 acc[8][2] = {};
  const float scale = 0.08838834764831845f;  // 1/sqrt(128)

  for (int t0 = 0; t0 < S_LEN; t0 += 64) {
    __syncthreads();  // prev tile's LDS reads complete
    const size_t krow0 = (size_t)(b * S_LEN + t0);
#pragma unroll
    for (int i = 0; i < 4; ++i) {  // K tile [64][128]
      int d = i * 4096 + tid * 16;
      int row = d >> 8;
      int colb = (d & 255) ^ ((row & 7) << 4);
      GLDS16(qkv + (krow0 + row) * QKVN + DMODEL + kvi * HD + (colb >> 1), (char*)Ks + d);
    }
#pragma unroll
    for (int i = 0; i < 4; ++i) {  // V^T tile [128][64]
      int d = i * 4096 + tid * 16;
      int row = d >> 7;
      int colb = (d & 127) ^ ((row & 7) << 4);
      GLDS16(vtb + (size_t)(kvi * HD + row) * MROWS + (size_t)(b * S_LEN + t0) + (colb >> 1),
             (char*)Vts + d);
    }
    __syncthreads();  // staged data visible (barrier drains vmcnt)

    // ---- S^T[key][q] = MFMA(K-frag, Q-frag) over d=128 ----
    fx4 st[4][2] = {};
#pragma unroll
    for (int kb2 = 0; kb2 < 4; ++kb2) {
      int krow = kb2 * 16 + opr;
      const char* kbase = (const char*)Ks + krow * 256;
      s16x8 kf[4];
#pragma unroll
      for (int kk = 0; kk < 4; ++kk)
        kf[kk] = *(const s16x8*)(kbase + ((kk * 64 + opk2) ^ ((krow & 7) << 4)));
#pragma unroll
      for (int qb = 0; qb < 2; ++qb)
#pragma unroll
        for (int kk = 0; kk < 4; ++kk)
          st[kb2][qb] = MFMA16(kf[kk], qf[qb][kk], st[kb2][qb]);
    }

    // ---- softmax per q-column ----
    float mloc[2], alpha[2], psum[2];
#pragma unroll
    for (int qb = 0; qb < 2; ++qb) {
      float mm = -1e30f;
#pragma unroll
      for (int kb2 = 0; kb2 < 4; ++kb2)
#pragma unroll
        for (int r = 0; r < 4; ++r) mm = fmaxf(mm, st[kb2][qb][r] * scale);
      mm = fmaxf(mm, __shfl_xor(mm, 16));
      mm = fmaxf(mm, __shfl_xor(mm, 32));
      mloc[qb] = mm;
      float mnew = fmaxf(m_run[qb], mm);
      alpha[qb] = __expf(m_run[qb] - mnew);   // first tile: exp(-huge) = 0
      m_run[qb] = mnew;
      psum[qb] = 0.f;
    }
#pragma unroll
    for (int db = 0; db < 8; ++db)
#pragma unroll
      for (int qb = 0; qb < 2; ++qb)
#pragma unroll
        for (int r = 0; r < 4; ++r) acc[db][qb][r] *= alpha[qb];

#pragma unroll
    for (int kb2 = 0; kb2 < 4; ++kb2)
#pragma unroll
      for (int qb = 0; qb < 2; ++qb)
#pragma unroll
        for (int r = 0; r < 4; ++r) {
          float pv = __expf(st[kb2][qb][r] * scale - m_run[qb]);
          psum[qb] += pv;
          Pw[(qb * 16 + cn) * 72 + kb2 * 16 + cm + r] = f2bf(pv);
        }
#pragma unroll
    for (int qb = 0; qb < 2; ++qb) {
      float s = psum[qb];
      s += __shfl_xor(s, 16);
      s += __shfl_xor(s, 32);
      l_run[qb] = l_run[qb] * alpha[qb] + s;
    }

    // ---- P b-frags (wave-private LDS, in-order within wave) ----
    s16x8 pf[2][2];
#pragma unroll
    for (int qb = 0; qb < 2; ++qb)
#pragma unroll
      for (int tb = 0; tb < 2; ++tb)
        pf[qb][tb] = *(const s16x8*)(Pw + (qb * 16 + opr) * 72 + tb * 32 + ak);

    // ---- O^T += MFMA(V^T-frag, P-frag) over t=64 ----
#pragma unroll
    for (int db = 0; db < 8; ++db) {
      int vrow = db * 16 + opr;
      const char* vbase = (const char*)Vts + vrow * 128;
      s16x8 vf[2];
#pragma unroll
      for (int tb = 0; tb < 2; ++tb)
        vf[tb] = *(const s16x8*)(vbase + ((tb * 64 + opk2) ^ ((vrow & 7) << 4)));
#pragma unroll
      for (int qb = 0; qb < 2; ++qb)
#pragma unroll
        for (int tb = 0; tb < 2; ++tb)
          acc[db][qb] = MFMA16(vf[tb], pf[qb][tb], acc[db][qb]);
    }
  }

  // ---- epilogue: normalize per q, pack 4 consecutive d -> 8B ----
  float inv[2] = {1.0f / l_run[0], 1.0f / l_run[1]};
#pragma unroll
  for (int db = 0; db < 8; ++db)
#pragma unroll
    for (int qb = 0; qb < 2; ++qb) {
      ushort4 o;
      o.x = f2bf(acc[db][qb][0] * inv[qb]);
      o.y = f2bf(acc[db][qb][1] * inv[qb]);
      o.z = f2bf(acc[db][qb][2] * inv[qb]);
      o.w = f2bf(acc[db][qb][3] * inv[qb]);
      *(ushort4*)(aob + (size_t)(qrow0 + qb * 16 + cn) * DMODEL + h * HD + db * 16 + cm) = o;
    }
}

// ---------------- launch ----------------
extern "C" void kernel_launch(void* const* d_in, const int* in_sizes, int n_in,
                              void* d_out, int out_size, void* d_ws, size_t ws_size,
                              hipStream_t stream) {
  const float* hs = (const float*)d_in[0];
  const float* fr = (const float*)d_in[1];
  const float* Wq = (const float*)d_in[2];
  const float* Wk = (const float*)d_in[3];
  const float* Wv = (const float*)d_in[4];
  const float* Wo = (const float*)d_in[5];
  const int* pos = (const int*)d_in[6];
  float* out = (float*)d_out;

  // workspace (bf16 elems), total 83,886,080 shorts = 167.8 MB
  unsigned short* w = (unsigned short*)d_ws;
  unsigned short* hsb   = w; w += 16777216;  // [4096,4096] hs bf16 (tab reuses after QKV gemm)
  unsigned short* wqkvb = w; w += 25165824;  // [6144,4096] Wq|Wk|Wv  (aob+vtb reuse after gemm)
  unsigned short* wob   = w; w += 16777216;  // [4096,4096]
  unsigned short* qkvb  = w; w += 25165824;  // [4096,6144] q|k|v per row (rope in-place)
  unsigned short* aob = wqkvb;               // [4096,4096] attn out
  unsigned short* vtb = wqkvb + 16777216;    // [1024,4096] V^T
  float2* tab = (float2*)hsb;                // [2048*64] cos/sin

  if (ws_size < (size_t)83886080 * 2) return;

  cast_all_k<<<57344, 256, 0, stream>>>(hs, Wq, Wk, Wv, Wo, hsb, wqkvb, wob);

  // fused QKV projection: [4096,4096] x [6144,4096]^T -> [4096,6144]
  gemm192<<<512, 512, 0, stream>>>(hsb, wqkvb, qkvb, MROWS, QKVN, DMODEL);

  rope_tab_k<<<512, 256, 0, stream>>>(fr, pos, tab);   // hsb dead now
  rope_k<<<40960, 256, 0, stream>>>(qkvb, tab);

  transpose_k<<<1024, 256, 0, stream>>>(qkvb + 5120, vtb, MROWS, 1024, QKVN);  // V -> V^T

  attn_mfma<<<1024, 256, 0, stream>>>(qkvb, vtb, aob);

  // output projection: [4096,4096] x [4096,4096]^T -> f32 out
  gemm256<<<256, 512, 0, stream>>>(aob, wob, out, nullptr, MROWS, DMODEL, DMODEL, 0);
}